// Round 9
// baseline (187.177 us; speedup 1.0000x reference)
//
#include <hip/hip_runtime.h>
#include <hip/hip_bf16.h>

#define NB 1024      // batch
#define NT 2         // time
#define NZ 100       // zones
#define NS 6         // state dim
#define NSEQ (NZ*NB) // actor sequences

typedef short short8 __attribute__((ext_vector_type(8)));
typedef float floatx4 __attribute__((ext_vector_type(4)));
typedef unsigned int uint2v __attribute__((ext_vector_type(2)));

__device__ __forceinline__ float sigm(float v)     { return 1.0f/(1.0f + __expf(-v)); }
__device__ __forceinline__ float tanhfast(float v) { float t = __expf(2.0f*v); return 1.0f - 2.0f/(t + 1.0f); }
__device__ __forceinline__ unsigned short f2bf(float f) {
    __hip_bfloat16 h = __float2bfloat16(f);
    return *reinterpret_cast<unsigned short*>(&h);
}

// ---------------- workspace byte offsets ----------------
#define WS_WIHB   819200                     // [192][32] bf16 (K 6->32)
#define WS_WHHB   (WS_WIHB + 192*32*2)       // [192][64]
#define WS_W1B    (WS_WHHB + 192*64*2)       // [512][64]
#define WS_W2B    (WS_W1B + 512*64*2)        // [128][512]
#define WS_L1WB   (WS_W2B + 128*512*2)       // [512][64]  (K 35->64)
#define WS_L2WB   (WS_L1WB + 512*64*2)       // [256][512]
#define WS_CF1WB  (WS_L2WB + 256*512*2)      // [512][32]
#define WS_CF2WB  (WS_CF1WB + 512*32*2)      // [256][512]
#define WS_CWIHB  (WS_CF2WB + 256*512*2)     // [96][64]   (K 35->64)
#define WS_CWHHB  (WS_CWIHB + 96*64*2)       // [96][32]
// end = WS_CWHHB + 96*32*2 = 1693696 B

#define PREP_N (116736 + 32768 + 131072 + 16384 + 131072 + 6144 + 3072)  // 437248

__global__ __launch_bounds__(256)
void prep_kernel(const float* __restrict__ wih, const float* __restrict__ whh,
                 const float* __restrict__ w1,  const float* __restrict__ w2,
                 const float* __restrict__ l1w, const float* __restrict__ l2w,
                 const float* __restrict__ cf1w, const float* __restrict__ cf2w,
                 const float* __restrict__ cwih, const float* __restrict__ cwhh,
                 unsigned short* wihb, unsigned short* whhb,
                 unsigned short* w1b,  unsigned short* w2b,
                 unsigned short* l1wb, unsigned short* l2wb,
                 unsigned short* cf1wb, unsigned short* cf2wb,
                 unsigned short* cwihb, unsigned short* cwhhb)
{
    int e = blockIdx.x*256 + threadIdx.x;
    if (e < 6144) {
        int g = e >> 5, k = e & 31;
        wihb[e] = f2bf(k < 6 ? wih[g*6 + k] : 0.0f);
    } else if (e < 18432) {
        int i = e - 6144;  whhb[i] = f2bf(whh[i]);
    } else if (e < 51200) {
        int i = e - 18432; w1b[i] = f2bf(w1[i]);
    } else if (e < 116736) {
        int i = e - 51200; w2b[i] = f2bf(w2[i]);
    } else if (e < 149504) {                    // l1wb [512][64] from [512][35]
        int i = e - 116736; int o = i >> 6, k = i & 63;
        l1wb[i] = f2bf(k < 35 ? l1w[o*35 + k] : 0.0f);
    } else if (e < 280576) {                    // l2wb copy
        int i = e - 149504; l2wb[i] = f2bf(l2w[i]);
    } else if (e < 296960) {                    // cf1wb copy
        int i = e - 280576; cf1wb[i] = f2bf(cf1w[i]);
    } else if (e < 428032) {                    // cf2wb copy
        int i = e - 296960; cf2wb[i] = f2bf(cf2w[i]);
    } else if (e < 434176) {                    // cwihb [96][64] from [96][35]
        int i = e - 428032; int o = i >> 6, k = i & 63;
        cwihb[i] = f2bf(k < 35 ? cwih[o*35 + k] : 0.0f);
    } else if (e < PREP_N) {                    // cwhhb copy
        int i = e - 434176; cwhhb[i] = f2bf(cwhh[i]);
    }
}

// swizzled bf16 LDS fragment read: 8 contiguous k at row r (XOR swizzle)
__device__ __forceinline__ short8 ldsfrag(const char* base, int rowstride, int r, int k0) {
    int byte = r*rowstride + k0*2;
    byte ^= ((r & 7) << 4);
    return *reinterpret_cast<const short8*>(base + byte);
}

// build GI B-fragment directly from global x (6 real values, k>=6 multiplied by
// zero A-columns so padding content is irrelevant)
__device__ __forceinline__ short8 xfrag(const float* __restrict__ xp) {
    float2 a  = *reinterpret_cast<const float2*>(xp);
    float2 b2 = *reinterpret_cast<const float2*>(xp + 2);
    float2 c  = *reinterpret_cast<const float2*>(xp + 4);
    short8 f;
    f[0] = (short)f2bf(a.x);  f[1] = (short)f2bf(a.y);
    f[2] = (short)f2bf(b2.x); f[3] = (short)f2bf(b2.y);
    f[4] = (short)f2bf(c.x);  f[5] = (short)f2bf(c.y);
    f[6] = 0; f[7] = 0;
    return f;
}

// ---------------------------------------------------------------------------
// Actor: 64 sequences (128 (seq,t) rows) per block, 8 waves, 7 barriers.
// GI B-operands built straight from global x (no staging phase). LDS 80 KB ->
// 2 blocks/CU; (512,4) = 128-VGPR cap, live set ~100 -> no spill.
// ---------------------------------------------------------------------------
__global__ __launch_bounds__(512, 4)
void actor_mfma(const float* __restrict__ x,
                const unsigned short* __restrict__ wihb, const unsigned short* __restrict__ whhb,
                const float* __restrict__ bih, const float* __restrict__ bhh,
                const unsigned short* __restrict__ w1b, const float* __restrict__ b1,
                const unsigned short* __restrict__ w2b, const float* __restrict__ b2,
                const float* __restrict__ w3, const float* __restrict__ b3,
                float* __restrict__ sa, float* __restrict__ out0)
{
    __shared__ __align__(16) char smem[81920];
    char*  sxb  = smem;              // [128 rows][64] bf16 stride 128 (GRU out; row = t*64+sl)
    float* fc3p = (float*)smem;      // [8][128] f32 (aliases sxb, written after FC2)
    char*  h1b  = smem + 16384;      // [128 rows][256 feats] bf16 stride 512 (half-tile)
    char*  h0b  = smem + 16384;      // [64 seq][64] bf16 stride 128 (aliases h1b; dead before FC1)

    const int tid  = threadIdx.x;
    const int wv   = tid >> 6;
    const int lane = tid & 63;
    const int r16  = lane & 15;
    const int g4   = lane >> 4;
    const int ft   = wv & 3;         // feature-triple: tiles {ft, ft+4, ft+8}
    const int sq   = wv >> 2;        // seq-tile group: tiles {sq*2, sq*2+1}
    const int s0   = blockIdx.x * 64;
    const int zz   = s0 >> 10;       // 64 | 1024 -> single z per block
    const int b0   = s0 & 1023;

    const int fb = ft*16 + g4*4;
    const floatx4 bihR = *reinterpret_cast<const floatx4*>(bih + fb);
    const floatx4 bihZ = *reinterpret_cast<const floatx4*>(bih + 64 + fb);
    const floatx4 bihN = *reinterpret_cast<const floatx4*>(bih + 128 + fb);
    const floatx4 bhhR = *reinterpret_cast<const floatx4*>(bhh + fb);
    const floatx4 bhhZ = *reinterpret_cast<const floatx4*>(bhh + 64 + fb);
    const floatx4 bhhN = *reinterpret_cast<const floatx4*>(bhh + 128 + fb);

    floatx4 h0[2];
    floatx4 g1R[2], g1Z[2], g1N[2];

    // ---- GI (t0 + t1) for both seq-tiles; GRU t0 in-register; no staging ----
    {
        const short8 aR = *reinterpret_cast<const short8*>(wihb + ((ft     )*16 + r16)*32 + g4*8);
        const short8 aZ = *reinterpret_cast<const short8*>(wihb + ((ft +  4)*16 + r16)*32 + g4*8);
        const short8 aN = *reinterpret_cast<const short8*>(wihb + ((ft +  8)*16 + r16)*32 + g4*8);
        #pragma unroll
        for (int u = 0; u < 2; ++u) {
            const int st  = sq*2 + u;
            const int seq = st*16 + r16;
            const int b   = b0 + seq;
            const float* xrow = x + ((b*NT)*NZ + zz)*NS;
            short8 bx0 = xfrag(xrow);                 // t = 0
            short8 bx1 = xfrag(xrow + NZ*NS);         // t = 1
            floatx4 gR = {0,0,0,0}, gZ = {0,0,0,0}, gN = {0,0,0,0};
            gR = __builtin_amdgcn_mfma_f32_16x16x32_bf16(aR, bx0, gR, 0, 0, 0);
            gZ = __builtin_amdgcn_mfma_f32_16x16x32_bf16(aZ, bx0, gZ, 0, 0, 0);
            gN = __builtin_amdgcn_mfma_f32_16x16x32_bf16(aN, bx0, gN, 0, 0, 0);
            floatx4 t1R = {0,0,0,0}, t1Z = {0,0,0,0}, t1N = {0,0,0,0};
            t1R = __builtin_amdgcn_mfma_f32_16x16x32_bf16(aR, bx1, t1R, 0, 0, 0);
            t1Z = __builtin_amdgcn_mfma_f32_16x16x32_bf16(aZ, bx1, t1Z, 0, 0, 0);
            t1N = __builtin_amdgcn_mfma_f32_16x16x32_bf16(aN, bx1, t1N, 0, 0, 0);
            g1R[u] = t1R; g1Z[u] = t1Z; g1N[u] = t1N;
            floatx4 hh;
            #pragma unroll
            for (int q = 0; q < 4; ++q) {
                float r = sigm(gR[q] + bihR[q] + bhhR[q]);
                float z = sigm(gZ[q] + bihZ[q] + bhhZ[q]);
                float n = tanhfast(gN[q] + bihN[q] + r*bhhN[q]);
                hh[q] = (1.0f - z)*n;
            }
            h0[u] = hh;
            unsigned int lo = (unsigned int)f2bf(hh[0]) | ((unsigned int)f2bf(hh[1]) << 16);
            unsigned int hi = (unsigned int)f2bf(hh[2]) | ((unsigned int)f2bf(hh[3]) << 16);
            uint2v vv = {lo, hi};
            int ba = seq*128 + fb*2; ba ^= ((seq & 7) << 4);
            *reinterpret_cast<uint2v*>(h0b + ba) = vv;    // for GH B-operand
            *reinterpret_cast<uint2v*>(sxb + ba) = vv;    // t0 GRU output (row = seq)
        }
    }
    __syncthreads();   // h0b ready

    // ---- GH + GRU t1 in-register for both seq-tiles ----
    {
        const short8 wR0 = *reinterpret_cast<const short8*>(whhb + ((ft     )*16 + r16)*64 + g4*8);
        const short8 wR1 = *reinterpret_cast<const short8*>(whhb + ((ft     )*16 + r16)*64 + 32 + g4*8);
        const short8 wZ0 = *reinterpret_cast<const short8*>(whhb + ((ft +  4)*16 + r16)*64 + g4*8);
        const short8 wZ1 = *reinterpret_cast<const short8*>(whhb + ((ft +  4)*16 + r16)*64 + 32 + g4*8);
        const short8 wN0 = *reinterpret_cast<const short8*>(whhb + ((ft +  8)*16 + r16)*64 + g4*8);
        const short8 wN1 = *reinterpret_cast<const short8*>(whhb + ((ft +  8)*16 + r16)*64 + 32 + g4*8);
        #pragma unroll
        for (int u = 0; u < 2; ++u) {
            const int st  = sq*2 + u;
            const int seq = st*16 + r16;
            short8 bh0 = ldsfrag(h0b, 128, seq, g4*8);
            short8 bh1 = ldsfrag(h0b, 128, seq, 32 + g4*8);
            floatx4 hR = {0,0,0,0}, hZ = {0,0,0,0}, hN = {0,0,0,0};
            hR = __builtin_amdgcn_mfma_f32_16x16x32_bf16(wR0, bh0, hR, 0, 0, 0);
            hZ = __builtin_amdgcn_mfma_f32_16x16x32_bf16(wZ0, bh0, hZ, 0, 0, 0);
            hN = __builtin_amdgcn_mfma_f32_16x16x32_bf16(wN0, bh0, hN, 0, 0, 0);
            hR = __builtin_amdgcn_mfma_f32_16x16x32_bf16(wR1, bh1, hR, 0, 0, 0);
            hZ = __builtin_amdgcn_mfma_f32_16x16x32_bf16(wZ1, bh1, hZ, 0, 0, 0);
            hN = __builtin_amdgcn_mfma_f32_16x16x32_bf16(wN1, bh1, hN, 0, 0, 0);
            floatx4 hn;
            #pragma unroll
            for (int q = 0; q < 4; ++q) {
                float r = sigm(g1R[u][q] + bihR[q] + hR[q] + bhhR[q]);
                float z = sigm(g1Z[u][q] + bihZ[q] + hZ[q] + bhhZ[q]);
                float n = tanhfast(g1N[u][q] + bihN[q] + r*(hN[q] + bhhN[q]));
                hn[q] = (1.0f - z)*n + z*h0[u][q];
            }
            unsigned int lo = (unsigned int)f2bf(hn[0]) | ((unsigned int)f2bf(hn[1]) << 16);
            unsigned int hi = (unsigned int)f2bf(hn[2]) | ((unsigned int)f2bf(hn[3]) << 16);
            uint2v vv = {lo, hi};
            int row = 64 + seq;
            int ba = row*128 + fb*2; ba ^= ((row & 7) << 4);
            *reinterpret_cast<uint2v*>(sxb + ba) = vv;
        }
    }
    __syncthreads();   // sxb all 128 rows ready; h0b dead -> h1b writable

    // ---- FC1/FC2 chunked: two halves of 256 features; acc[8] in registers ----
    floatx4 acc[8];
    {
        const floatx4 bias2 = *reinterpret_cast<const floatx4*>(b2 + wv*16 + g4*4);
        #pragma unroll
        for (int rt = 0; rt < 8; ++rt) acc[rt] = bias2;
    }

    #pragma unroll
    for (int h = 0; h < 2; ++h) {
        // FC1 half h: features h*256 .. h*256+255 (wave owns 2 ftiles, 8 row-tiles)
        #pragma unroll
        for (int rt = 0; rt < 8; ++rt) {
            short8 f0 = ldsfrag(sxb, 128, rt*16 + r16, g4*8);
            short8 f1 = ldsfrag(sxb, 128, rt*16 + r16, 32 + g4*8);
            #pragma unroll
            for (int j = 0; j < 2; ++j) {
                int mtg = h*16 + wv*2 + j;     // global ftile (0..31)
                int mtl = wv*2 + j;            // local col tile in h1b (0..15)
                const short8 a0 = *reinterpret_cast<const short8*>(w1b + (mtg*16 + r16)*64 + g4*8);
                const short8 a1 = *reinterpret_cast<const short8*>(w1b + (mtg*16 + r16)*64 + 32 + g4*8);
                floatx4 a = *reinterpret_cast<const floatx4*>(b1 + mtg*16 + g4*4);
                a = __builtin_amdgcn_mfma_f32_16x16x32_bf16(a0, f0, a, 0, 0, 0);
                a = __builtin_amdgcn_mfma_f32_16x16x32_bf16(a1, f1, a, 0, 0, 0);
                unsigned int lo = (unsigned int)f2bf(fmaxf(a[0],0.f)) | ((unsigned int)f2bf(fmaxf(a[1],0.f)) << 16);
                unsigned int hi = (unsigned int)f2bf(fmaxf(a[2],0.f)) | ((unsigned int)f2bf(fmaxf(a[3],0.f)) << 16);
                int row = rt*16 + r16;
                int byte = row*512 + (mtl*16 + g4*4)*2; byte ^= ((row & 7) << 4);
                uint2v vv = {lo, hi};
                *reinterpret_cast<uint2v*>(h1b + byte) = vv;
            }
        }
        __syncthreads();   // h1b (this half) ready

        // FC2 accumulate over this half's 256 features (8 k-steps, 8 row-tiles)
        {
            const unsigned short* wp = w2b + (wv*16 + r16)*512 + h*256 + g4*8;
            #pragma unroll
            for (int ks = 0; ks < 8; ++ks) {
                const short8 a = *reinterpret_cast<const short8*>(wp + ks*32);
                #pragma unroll
                for (int rt = 0; rt < 8; ++rt) {
                    short8 bb = ldsfrag(h1b, 512, rt*16 + r16, ks*32 + g4*8);
                    acc[rt] = __builtin_amdgcn_mfma_f32_16x16x32_bf16(a, bb, acc[rt], 0, 0, 0);
                }
            }
        }
        __syncthreads();   // h1b reads done -> next half may overwrite / fc3p writable
    }

    // ---- fused FC3 partial ----
    {
        const floatx4 w3v = *reinterpret_cast<const floatx4*>(w3 + wv*16 + g4*4);
        #pragma unroll
        for (int rt = 0; rt < 8; ++rt) {
            float p = fmaxf(acc[rt][0],0.f)*w3v[0] + fmaxf(acc[rt][1],0.f)*w3v[1]
                    + fmaxf(acc[rt][2],0.f)*w3v[2] + fmaxf(acc[rt][3],0.f)*w3v[3];
            p += __shfl_xor(p, 16);
            p += __shfl_xor(p, 32);
            if (g4 == 0) fc3p[wv*128 + rt*16 + r16] = p;
        }
    }
    __syncthreads();

    // ---- final: per row, sum 8 wave-partials + b3; write sa (+ out0 gather) ----
    if (tid < 128) {
        float v = b3[0];
        #pragma unroll
        for (int w = 0; w < 8; ++w) v += fc3p[w*128 + tid];
        int t = tid >> 6, sl = tid & 63;
        int gseq = s0 + sl;
        int i = gseq*2 + t;
        sa[i] = v;
        int m = i % 200;
        if (m >= 100) out0[(i/200)*NZ + (m - 100)] = v;
    }
}

// ---------------------------------------------------------------------------
// Critic MFMA: 16 batch rows per block × 64 blocks, 8 waves — unchanged
// ---------------------------------------------------------------------------
__global__ __launch_bounds__(512)
void critic_mfma(const float* __restrict__ x, const float* __restrict__ sa,
                 const unsigned short* __restrict__ cwihb, const unsigned short* __restrict__ cwhhb,
                 const float* __restrict__ cbih, const float* __restrict__ cbhh,
                 const unsigned short* __restrict__ cf1wb, const float* __restrict__ cf1b,
                 const unsigned short* __restrict__ cf2wb, const float* __restrict__ cf2b,
                 const float* __restrict__ cf3w, const float* __restrict__ cf3b,
                 const unsigned short* __restrict__ l1wb, const float* __restrict__ l1b,
                 const unsigned short* __restrict__ l2wb, const float* __restrict__ l2b,
                 const float* __restrict__ l3w, const float* __restrict__ l3b,
                 float* __restrict__ outq)
{
    __shared__ __align__(16) char smem[25600];
    char*  xib = smem;                    // [32 trow][64] bf16 stride 128
    char*  h1b = smem + 4096;             // [16][512] bf16 stride 1024
    char*  h0b = smem + 20480;            // [16][64B] stride 128
    char*  hqb = smem + 22528;            // [16][64B] stride 128
    float* fp  = (float*)(smem + 24576);  // [8][16]
    float* qp  = (float*)(smem + 25088);  // [8][16]

    const int tid  = threadIdx.x;
    const int wv   = tid >> 6;
    const int lane = tid & 63;
    const int r16  = lane & 15;
    const int g4   = lane >> 4;
    const int b0   = blockIdx.x * 16;

    for (int e = tid; e < 2048; e += 512) {
        int trow = e >> 6, k = e & 63;
        int t = trow >> 4, row = trow & 15;
        int b = b0 + row;
        float v = 0.0f;
        if (k < 35) {
            int slot = k / 7, s = k - slot*7;
            int nb = (slot==0)?99:((slot==1)?89:((slot==4)?98:-1));
            if (nb >= 0) v = (s < 6) ? x[((b*NT + t)*NZ + nb)*NS + s]
                                     : sa[b*200 + t*100 + nb];
        }
        int byte = trow*128 + k*2; byte ^= ((trow & 7) << 4);
        *reinterpret_cast<unsigned short*>(xib + byte) = f2bf(v);
    }
    __syncthreads();

    {
        short8 bx0 = ldsfrag(xib, 128, 16 + r16, g4*8);
        short8 bx1 = ldsfrag(xib, 128, 16 + r16, 32 + g4*8);
        #pragma unroll
        for (int j = 0; j < 4; ++j) {
            int mt = wv*4 + j;
            const short8 a0 = *reinterpret_cast<const short8*>(l1wb + (mt*16 + r16)*64 + g4*8);
            const short8 a1 = *reinterpret_cast<const short8*>(l1wb + (mt*16 + r16)*64 + 32 + g4*8);
            floatx4 acc = *reinterpret_cast<const floatx4*>(l1b + mt*16 + g4*4);
            acc = __builtin_amdgcn_mfma_f32_16x16x32_bf16(a0, bx0, acc, 0, 0, 0);
            acc = __builtin_amdgcn_mfma_f32_16x16x32_bf16(a1, bx1, acc, 0, 0, 0);
            unsigned int lo = (unsigned int)f2bf(fmaxf(acc[0],0.f)) | ((unsigned int)f2bf(fmaxf(acc[1],0.f)) << 16);
            unsigned int hi = (unsigned int)f2bf(fmaxf(acc[2],0.f)) | ((unsigned int)f2bf(fmaxf(acc[3],0.f)) << 16);
            int byte = r16*1024 + (mt*16 + g4*4)*2; byte ^= ((r16 & 7) << 4);
            uint2v vv = {lo, hi};
            *reinterpret_cast<uint2v*>(h1b + byte) = vv;
        }
    }
    __syncthreads();

    {
        int mt0 = wv*2, mt1 = wv*2 + 1;
        floatx4 acc0 = *reinterpret_cast<const floatx4*>(l2b + mt0*16 + g4*4);
        floatx4 acc1 = *reinterpret_cast<const floatx4*>(l2b + mt1*16 + g4*4);
        const unsigned short* wp0 = l2wb + (mt0*16 + r16)*512 + g4*8;
        const unsigned short* wp1 = l2wb + (mt1*16 + r16)*512 + g4*8;
        for (int ks = 0; ks < 16; ++ks) {
            short8 bb = ldsfrag(h1b, 1024, r16, ks*32 + g4*8);
            const short8 a0 = *reinterpret_cast<const short8*>(wp0 + ks*32);
            const short8 a1 = *reinterpret_cast<const short8*>(wp1 + ks*32);
            acc0 = __builtin_amdgcn_mfma_f32_16x16x32_bf16(a0, bb, acc0, 0, 0, 0);
            acc1 = __builtin_amdgcn_mfma_f32_16x16x32_bf16(a1, bb, acc1, 0, 0, 0);
        }
        const floatx4 w0 = *reinterpret_cast<const floatx4*>(l3w + mt0*16 + g4*4);
        const floatx4 w1 = *reinterpret_cast<const floatx4*>(l3w + mt1*16 + g4*4);
        float p = fmaxf(acc0[0],0.f)*w0[0] + fmaxf(acc0[1],0.f)*w0[1]
                + fmaxf(acc0[2],0.f)*w0[2] + fmaxf(acc0[3],0.f)*w0[3]
                + fmaxf(acc1[0],0.f)*w1[0] + fmaxf(acc1[1],0.f)*w1[1]
                + fmaxf(acc1[2],0.f)*w1[2] + fmaxf(acc1[3],0.f)*w1[3];
        p += __shfl_xor(p, 16);
        p += __shfl_xor(p, 32);
        if (g4 == 0) fp[wv*16 + r16] = p;
    }
    __syncthreads();

    floatx4 h0r = {0,0,0,0};
    floatx4 gR1 = {0,0,0,0}, gZ1 = {0,0,0,0}, gN1 = {0,0,0,0};
    floatx4 bihR, bihZ, bihN, bhhR, bhhZ, bhhN;
    if (wv < 2) {
        const int hf = wv;
        const int fb = hf*16 + g4*4;
        bihR = *reinterpret_cast<const floatx4*>(cbih + fb);
        bihZ = *reinterpret_cast<const floatx4*>(cbih + 32 + fb);
        bihN = *reinterpret_cast<const floatx4*>(cbih + 64 + fb);
        bhhR = *reinterpret_cast<const floatx4*>(cbhh + fb);
        bhhZ = *reinterpret_cast<const floatx4*>(cbhh + 32 + fb);
        bhhN = *reinterpret_cast<const floatx4*>(cbhh + 64 + fb);
        short8 bx0 = ldsfrag(xib, 128, r16, g4*8);
        short8 bx1 = ldsfrag(xib, 128, r16, 32 + g4*8);
        short8 cx0 = ldsfrag(xib, 128, 16 + r16, g4*8);
        short8 cx1 = ldsfrag(xib, 128, 16 + r16, 32 + g4*8);
        floatx4 gR0 = {0,0,0,0}, gZ0 = {0,0,0,0}, gN0 = {0,0,0,0};
        #pragma unroll
        for (int p = 0; p < 2; ++p) {
            const short8 aR = *reinterpret_cast<const short8*>(cwihb + ((hf    )*16 + r16)*64 + p*32 + g4*8);
            const short8 aZ = *reinterpret_cast<const short8*>(cwihb + ((2+hf  )*16 + r16)*64 + p*32 + g4*8);
            const short8 aN = *reinterpret_cast<const short8*>(cwihb + ((4+hf  )*16 + r16)*64 + p*32 + g4*8);
            short8 b0f = p ? bx1 : bx0;
            short8 b1f = p ? cx1 : cx0;
            gR0 = __builtin_amdgcn_mfma_f32_16x16x32_bf16(aR, b0f, gR0, 0, 0, 0);
            gZ0 = __builtin_amdgcn_mfma_f32_16x16x32_bf16(aZ, b0f, gZ0, 0, 0, 0);
            gN0 = __builtin_amdgcn_mfma_f32_16x16x32_bf16(aN, b0f, gN0, 0, 0, 0);
            gR1 = __builtin_amdgcn_mfma_f32_16x16x32_bf16(aR, b1f, gR1, 0, 0, 0);
            gZ1 = __builtin_amdgcn_mfma_f32_16x16x32_bf16(aZ, b1f, gZ1, 0, 0, 0);
            gN1 = __builtin_amdgcn_mfma_f32_16x16x32_bf16(aN, b1f, gN1, 0, 0, 0);
        }
        #pragma unroll
        for (int q = 0; q < 4; ++q) {
            float r = sigm(gR0[q] + bihR[q] + bhhR[q]);
            float z = sigm(gZ0[q] + bihZ[q] + bhhZ[q]);
            float n = tanhfast(gN0[q] + bihN[q] + r*bhhN[q]);
            h0r[q] = (1.0f - z)*n;
        }
        unsigned int lo = (unsigned int)f2bf(h0r[0]) | ((unsigned int)f2bf(h0r[1]) << 16);
        unsigned int hi = (unsigned int)f2bf(h0r[2]) | ((unsigned int)f2bf(h0r[3]) << 16);
        uint2v vv = {lo, hi};
        int byte = r16*128 + fb*2; byte ^= ((r16 & 7) << 4);
        *reinterpret_cast<uint2v*>(h0b + byte) = vv;
    }
    __syncthreads();
    if (wv < 2) {
        const int hf = wv;
        const int fb = hf*16 + g4*4;
        short8 bh = ldsfrag(h0b, 128, r16, g4*8);
        const short8 aR = *reinterpret_cast<const short8*>(cwhhb + ((hf    )*16 + r16)*32 + g4*8);
        const short8 aZ = *reinterpret_cast<const short8*>(cwhhb + ((2+hf  )*16 + r16)*32 + g4*8);
        const short8 aN = *reinterpret_cast<const short8*>(cwhhb + ((4+hf  )*16 + r16)*32 + g4*8);
        floatx4 hR = {0,0,0,0}, hZ = {0,0,0,0}, hN = {0,0,0,0};
        hR = __builtin_amdgcn_mfma_f32_16x16x32_bf16(aR, bh, hR, 0, 0, 0);
        hZ = __builtin_amdgcn_mfma_f32_16x16x32_bf16(aZ, bh, hZ, 0, 0, 0);
        hN = __builtin_amdgcn_mfma_f32_16x16x32_bf16(aN, bh, hN, 0, 0, 0);
        floatx4 hn;
        #pragma unroll
        for (int q = 0; q < 4; ++q) {
            float r = sigm(gR1[q] + bihR[q] + hR[q] + bhhR[q]);
            float z = sigm(gZ1[q] + bihZ[q] + hZ[q] + bhhZ[q]);
            float n = tanhfast(gN1[q] + bihN[q] + r*(hN[q] + bhhN[q]));
            hn[q] = (1.0f - z)*n + z*h0r[q];
        }
        unsigned int lo = (unsigned int)f2bf(hn[0]) | ((unsigned int)f2bf(hn[1]) << 16);
        unsigned int hi = (unsigned int)f2bf(hn[2]) | ((unsigned int)f2bf(hn[3]) << 16);
        uint2v vv = {lo, hi};
        int byte = r16*128 + fb*2; byte ^= ((r16 & 7) << 4);
        *reinterpret_cast<uint2v*>(hqb + byte) = vv;
    }
    __syncthreads();

    {
        short8 bq = ldsfrag(hqb, 128, r16, g4*8);
        #pragma unroll
        for (int j = 0; j < 4; ++j) {
            int mt = wv*4 + j;
            const short8 a = *reinterpret_cast<const short8*>(cf1wb + (mt*16 + r16)*32 + g4*8);
            floatx4 acc = *reinterpret_cast<const floatx4*>(cf1b + mt*16 + g4*4);
            acc = __builtin_amdgcn_mfma_f32_16x16x32_bf16(a, bq, acc, 0, 0, 0);
            unsigned int lo = (unsigned int)f2bf(fmaxf(acc[0],0.f)) | ((unsigned int)f2bf(fmaxf(acc[1],0.f)) << 16);
            unsigned int hi = (unsigned int)f2bf(fmaxf(acc[2],0.f)) | ((unsigned int)f2bf(fmaxf(acc[3],0.f)) << 16);
            int byte = r16*1024 + (mt*16 + g4*4)*2; byte ^= ((r16 & 7) << 4);
            uint2v vv = {lo, hi};
            *reinterpret_cast<uint2v*>(h1b + byte) = vv;
        }
    }
    __syncthreads();

    {
        int mt0 = wv*2, mt1 = wv*2 + 1;
        floatx4 acc0 = *reinterpret_cast<const floatx4*>(cf2b + mt0*16 + g4*4);
        floatx4 acc1 = *reinterpret_cast<const floatx4*>(cf2b + mt1*16 + g4*4);
        const unsigned short* wp0 = cf2wb + (mt0*16 + r16)*512 + g4*8;
        const unsigned short* wp1 = cf2wb + (mt1*16 + r16)*512 + g4*8;
        for (int ks = 0; ks < 16; ++ks) {
            short8 bb = ldsfrag(h1b, 1024, r16, ks*32 + g4*8);
            const short8 a0 = *reinterpret_cast<const short8*>(wp0 + ks*32);
            const short8 a1 = *reinterpret_cast<const short8*>(wp1 + ks*32);
            acc0 = __builtin_amdgcn_mfma_f32_16x16x32_bf16(a0, bb, acc0, 0, 0, 0);
            acc1 = __builtin_amdgcn_mfma_f32_16x16x32_bf16(a1, bb, acc1, 0, 0, 0);
        }
        const floatx4 w0 = *reinterpret_cast<const floatx4*>(cf3w + mt0*16 + g4*4);
        const floatx4 w1 = *reinterpret_cast<const floatx4*>(cf3w + mt1*16 + g4*4);
        float p = fmaxf(acc0[0],0.f)*w0[0] + fmaxf(acc0[1],0.f)*w0[1]
                + fmaxf(acc0[2],0.f)*w0[2] + fmaxf(acc0[3],0.f)*w0[3]
                + fmaxf(acc1[0],0.f)*w1[0] + fmaxf(acc1[1],0.f)*w1[1]
                + fmaxf(acc1[2],0.f)*w1[2] + fmaxf(acc1[3],0.f)*w1[3];
        p += __shfl_xor(p, 16);
        p += __shfl_xor(p, 32);
        if (g4 == 0) qp[wv*16 + r16] = p;
    }
    __syncthreads();

    if (tid < 16) {
        float f = l3b[0], qz = cf3b[0];
        #pragma unroll
        for (int w = 0; w < 8; ++w) { f += fp[w*16 + tid]; qz += qp[w*16 + tid]; }
        outq[b0 + tid] = f + qz;
    }
}

extern "C" void kernel_launch(void* const* d_in, const int* in_sizes, int n_in,
                              void* d_out, int out_size, void* d_ws, size_t ws_size,
                              hipStream_t stream)
{
    (void)in_sizes; (void)n_in; (void)out_size; (void)ws_size;
    const float* x     = (const float*)d_in[0];
    const float* a_wih = (const float*)d_in[1];
    const float* a_whh = (const float*)d_in[2];
    const float* a_bih = (const float*)d_in[3];
    const float* a_bhh = (const float*)d_in[4];
    const float* a1w   = (const float*)d_in[5];
    const float* a1b   = (const float*)d_in[6];
    const float* a2w   = (const float*)d_in[7];
    const float* a2b   = (const float*)d_in[8];
    const float* a3w   = (const float*)d_in[9];
    const float* a3b   = (const float*)d_in[10];
    const float* cwih  = (const float*)d_in[11];
    const float* cwhh  = (const float*)d_in[12];
    const float* cbih  = (const float*)d_in[13];
    const float* cbhh  = (const float*)d_in[14];
    const float* cf1w  = (const float*)d_in[15];
    const float* cf1b  = (const float*)d_in[16];
    const float* cf2w  = (const float*)d_in[17];
    const float* cf2b  = (const float*)d_in[18];
    const float* cf3w  = (const float*)d_in[19];
    const float* cf3b  = (const float*)d_in[20];
    const float* l1w   = (const float*)d_in[21];
    const float* l1b   = (const float*)d_in[22];
    const float* l2w   = (const float*)d_in[23];
    const float* l2b   = (const float*)d_in[24];
    const float* l3w   = (const float*)d_in[25];
    const float* l3b   = (const float*)d_in[26];

    float* sa = (float*)d_ws;
    unsigned short* wihb  = (unsigned short*)((char*)d_ws + WS_WIHB);
    unsigned short* whhb  = (unsigned short*)((char*)d_ws + WS_WHHB);
    unsigned short* w1b   = (unsigned short*)((char*)d_ws + WS_W1B);
    unsigned short* w2b   = (unsigned short*)((char*)d_ws + WS_W2B);
    unsigned short* l1wb  = (unsigned short*)((char*)d_ws + WS_L1WB);
    unsigned short* l2wb  = (unsigned short*)((char*)d_ws + WS_L2WB);
    unsigned short* cf1wb = (unsigned short*)((char*)d_ws + WS_CF1WB);
    unsigned short* cf2wb = (unsigned short*)((char*)d_ws + WS_CF2WB);
    unsigned short* cwihb = (unsigned short*)((char*)d_ws + WS_CWIHB);
    unsigned short* cwhhb = (unsigned short*)((char*)d_ws + WS_CWHHB);
    float* out0 = (float*)d_out;
    float* outq = (float*)d_out + NB*NZ;

    hipLaunchKernelGGL(prep_kernel, dim3((PREP_N + 255)/256), dim3(256), 0, stream,
                       a_wih, a_whh, a1w, a2w, l1w, l2w, cf1w, cf2w, cwih, cwhh,
                       wihb, whhb, w1b, w2b, l1wb, l2wb, cf1wb, cf2wb, cwihb, cwhhb);
    hipLaunchKernelGGL(actor_mfma, dim3(NSEQ/64), dim3(512), 0, stream,
                       x, wihb, whhb, a_bih, a_bhh, w1b, a1b, w2b, a2b, a3w, a3b, sa, out0);
    hipLaunchKernelGGL(critic_mfma, dim3(NB/16), dim3(512), 0, stream,
                       x, sa, cwihb, cwhhb, cbih, cbhh, cf1wb, cf1b, cf2wb, cf2b, cf3w, cf3b,
                       l1wb, l1b, l2wb, l2b, l3w, l3b, outq);
}

// Round 10
// 152.988 us; speedup vs baseline: 1.2235x; 1.2235x over previous
//
#include <hip/hip_runtime.h>
#include <hip/hip_bf16.h>

#define NB 1024      // batch
#define NT 2         // time
#define NZ 100       // zones
#define NS 6         // state dim
#define NSEQ (NZ*NB) // actor sequences

typedef short short8 __attribute__((ext_vector_type(8)));
typedef float floatx4 __attribute__((ext_vector_type(4)));
typedef unsigned int uint2v __attribute__((ext_vector_type(2)));

__device__ __forceinline__ float sigm(float v)     { return 1.0f/(1.0f + __expf(-v)); }
__device__ __forceinline__ float tanhfast(float v) { float t = __expf(2.0f*v); return 1.0f - 2.0f/(t + 1.0f); }
__device__ __forceinline__ unsigned short f2bf(float f) {
    __hip_bfloat16 h = __float2bfloat16(f);
    return *reinterpret_cast<unsigned short*>(&h);
}

// ---------------- workspace byte offsets ----------------
#define WS_WIHB   819200                     // [192][32] bf16 (K 6->32)
#define WS_WHHB   (WS_WIHB + 192*32*2)       // [192][64]
#define WS_W1B    (WS_WHHB + 192*64*2)       // [512][64]
#define WS_W2B    (WS_W1B + 512*64*2)        // [128][512]
#define WS_L1WB   (WS_W2B + 128*512*2)       // [512][64]  (K 35->64)
#define WS_L2WB   (WS_L1WB + 512*64*2)       // [256][512]
#define WS_CF1WB  (WS_L2WB + 256*512*2)      // [512][32]
#define WS_CF2WB  (WS_CF1WB + 512*32*2)      // [256][512]
#define WS_CWIHB  (WS_CF2WB + 256*512*2)     // [96][64]   (K 35->64)
#define WS_CWHHB  (WS_CWIHB + 96*64*2)       // [96][32]
// end = WS_CWHHB + 96*32*2 = 1693696 B

#define PREP_N (116736 + 32768 + 131072 + 16384 + 131072 + 6144 + 3072)  // 437248

__global__ __launch_bounds__(256)
void prep_kernel(const float* __restrict__ wih, const float* __restrict__ whh,
                 const float* __restrict__ w1,  const float* __restrict__ w2,
                 const float* __restrict__ l1w, const float* __restrict__ l2w,
                 const float* __restrict__ cf1w, const float* __restrict__ cf2w,
                 const float* __restrict__ cwih, const float* __restrict__ cwhh,
                 unsigned short* wihb, unsigned short* whhb,
                 unsigned short* w1b,  unsigned short* w2b,
                 unsigned short* l1wb, unsigned short* l2wb,
                 unsigned short* cf1wb, unsigned short* cf2wb,
                 unsigned short* cwihb, unsigned short* cwhhb)
{
    int e = blockIdx.x*256 + threadIdx.x;
    if (e < 6144) {
        int g = e >> 5, k = e & 31;
        wihb[e] = f2bf(k < 6 ? wih[g*6 + k] : 0.0f);
    } else if (e < 18432) {
        int i = e - 6144;  whhb[i] = f2bf(whh[i]);
    } else if (e < 51200) {
        int i = e - 18432; w1b[i] = f2bf(w1[i]);
    } else if (e < 116736) {
        int i = e - 51200; w2b[i] = f2bf(w2[i]);
    } else if (e < 149504) {                    // l1wb [512][64] from [512][35]
        int i = e - 116736; int o = i >> 6, k = i & 63;
        l1wb[i] = f2bf(k < 35 ? l1w[o*35 + k] : 0.0f);
    } else if (e < 280576) {                    // l2wb copy
        int i = e - 149504; l2wb[i] = f2bf(l2w[i]);
    } else if (e < 296960) {                    // cf1wb copy
        int i = e - 280576; cf1wb[i] = f2bf(cf1w[i]);
    } else if (e < 428032) {                    // cf2wb copy
        int i = e - 296960; cf2wb[i] = f2bf(cf2w[i]);
    } else if (e < 434176) {                    // cwihb [96][64] from [96][35]
        int i = e - 428032; int o = i >> 6, k = i & 63;
        cwihb[i] = f2bf(k < 35 ? cwih[o*35 + k] : 0.0f);
    } else if (e < PREP_N) {                    // cwhhb copy
        int i = e - 434176; cwhhb[i] = f2bf(cwhh[i]);
    }
}

// two-bit XOR swizzle mask for row r (breaks 8-lane bank grouping too)
__device__ __forceinline__ int swz(int r) { return ((r & 7) << 4) | ((r & 8) << 3); }

// swizzled bf16 LDS fragment read: 8 contiguous k at row r
__device__ __forceinline__ short8 ldsfrag(const char* base, int rowstride, int r, int k0) {
    int byte = r*rowstride + k0*2;
    byte ^= swz(r);
    return *reinterpret_cast<const short8*>(base + byte);
}

// legacy 1-bit swizzle (critic kernel, unchanged layout)
__device__ __forceinline__ short8 ldsfragC(const char* base, int rowstride, int r, int k0) {
    int byte = r*rowstride + k0*2;
    byte ^= ((r & 7) << 4);
    return *reinterpret_cast<const short8*>(base + byte);
}

// build GI B-fragment directly from global x; k>=6 pairs with zero A-columns
__device__ __forceinline__ short8 xfrag(const float* __restrict__ xp) {
    float2 a  = *reinterpret_cast<const float2*>(xp);
    float2 b2 = *reinterpret_cast<const float2*>(xp + 2);
    float2 c  = *reinterpret_cast<const float2*>(xp + 4);
    short8 f;
    f[0] = (short)f2bf(a.x);  f[1] = (short)f2bf(a.y);
    f[2] = (short)f2bf(b2.x); f[3] = (short)f2bf(b2.y);
    f[4] = (short)f2bf(c.x);  f[5] = (short)f2bf(c.y);
    f[6] = 0; f[7] = 0;
    return f;
}

// ---------------------------------------------------------------------------
// Actor: 32 seqs (64 rows, row = t*32+sl) per 256-thread block (4 waves).
// LDS 24576 B -> 6 blocks/CU potential (24 waves). FC1/FC2 in 128-feature
// quarters; FC2 acc[2][4] persists in registers. No launch-bounds min-waves
// (R6/R7/R9 lesson: forcing occupancy makes the allocator spill).
// ---------------------------------------------------------------------------
__global__ __launch_bounds__(256)
void actor_mfma(const float* __restrict__ x,
                const unsigned short* __restrict__ wihb, const unsigned short* __restrict__ whhb,
                const float* __restrict__ bih, const float* __restrict__ bhh,
                const unsigned short* __restrict__ w1b, const float* __restrict__ b1,
                const unsigned short* __restrict__ w2b, const float* __restrict__ b2,
                const float* __restrict__ w3, const float* __restrict__ b3,
                float* __restrict__ sa, float* __restrict__ out0)
{
    __shared__ __align__(16) char smem[24576];
    char*  sxb  = smem;              // [64 rows][64] bf16 stride 128 (GRU out)
    float* fc3p = (float*)smem;      // [4][64] f32 (aliases sxb; written after FC2 q=3)
    char*  h1q  = smem + 8192;       // [64 rows][128 feats] bf16 stride 256 (quarter)
    char*  h0b  = smem + 8192;       // [32 seq][64] bf16 stride 128 (aliases h1q; dead pre-FC1)

    const int tid  = threadIdx.x;
    const int wv   = tid >> 6;       // 0..3 = feature-triple ft
    const int lane = tid & 63;
    const int r16  = lane & 15;
    const int g4   = lane >> 4;
    const int ft   = wv;
    const int s0   = blockIdx.x * 32;
    const int zz   = s0 >> 10;
    const int b0   = s0 & 1023;

    const int fb = ft*16 + g4*4;
    const floatx4 bihR = *reinterpret_cast<const floatx4*>(bih + fb);
    const floatx4 bihZ = *reinterpret_cast<const floatx4*>(bih + 64 + fb);
    const floatx4 bihN = *reinterpret_cast<const floatx4*>(bih + 128 + fb);
    const floatx4 bhhR = *reinterpret_cast<const floatx4*>(bhh + fb);
    const floatx4 bhhZ = *reinterpret_cast<const floatx4*>(bhh + 64 + fb);
    const floatx4 bhhN = *reinterpret_cast<const floatx4*>(bhh + 128 + fb);

    floatx4 h0v[2];
    floatx4 g1R[2], g1Z[2], g1N[2];

    // ---- GI (t0+t1), GRU t0 in-register; both seq-tiles; x direct from global ----
    {
        const short8 aR = *reinterpret_cast<const short8*>(wihb + ((ft     )*16 + r16)*32 + g4*8);
        const short8 aZ = *reinterpret_cast<const short8*>(wihb + ((ft +  4)*16 + r16)*32 + g4*8);
        const short8 aN = *reinterpret_cast<const short8*>(wihb + ((ft +  8)*16 + r16)*32 + g4*8);
        #pragma unroll
        for (int u = 0; u < 2; ++u) {
            const int seq = u*16 + r16;
            const float* xrow = x + (((b0 + seq)*NT)*NZ + zz)*NS;
            short8 bx0 = xfrag(xrow);            // t=0
            short8 bx1 = xfrag(xrow + NZ*NS);    // t=1
            floatx4 gR = {0,0,0,0}, gZ = {0,0,0,0}, gN = {0,0,0,0};
            gR = __builtin_amdgcn_mfma_f32_16x16x32_bf16(aR, bx0, gR, 0, 0, 0);
            gZ = __builtin_amdgcn_mfma_f32_16x16x32_bf16(aZ, bx0, gZ, 0, 0, 0);
            gN = __builtin_amdgcn_mfma_f32_16x16x32_bf16(aN, bx0, gN, 0, 0, 0);
            floatx4 tR = {0,0,0,0}, tZ = {0,0,0,0}, tN = {0,0,0,0};
            tR = __builtin_amdgcn_mfma_f32_16x16x32_bf16(aR, bx1, tR, 0, 0, 0);
            tZ = __builtin_amdgcn_mfma_f32_16x16x32_bf16(aZ, bx1, tZ, 0, 0, 0);
            tN = __builtin_amdgcn_mfma_f32_16x16x32_bf16(aN, bx1, tN, 0, 0, 0);
            g1R[u] = tR; g1Z[u] = tZ; g1N[u] = tN;
            floatx4 hh;
            #pragma unroll
            for (int q = 0; q < 4; ++q) {
                float r = sigm(gR[q] + bihR[q] + bhhR[q]);
                float z = sigm(gZ[q] + bihZ[q] + bhhZ[q]);
                float n = tanhfast(gN[q] + bihN[q] + r*bhhN[q]);
                hh[q] = (1.0f - z)*n;
            }
            h0v[u] = hh;
            unsigned int lo = (unsigned int)f2bf(hh[0]) | ((unsigned int)f2bf(hh[1]) << 16);
            unsigned int hi = (unsigned int)f2bf(hh[2]) | ((unsigned int)f2bf(hh[3]) << 16);
            uint2v vv = {lo, hi};
            int ba = seq*128 + fb*2; ba ^= swz(seq);
            *reinterpret_cast<uint2v*>(h0b + ba) = vv;    // GH B-operand
            *reinterpret_cast<uint2v*>(sxb + ba) = vv;    // t0 GRU output (row=seq)
        }
    }
    __syncthreads();   // h0b ready

    // ---- GH + GRU t1 in-register ----
    {
        const short8 wR0 = *reinterpret_cast<const short8*>(whhb + ((ft     )*16 + r16)*64 + g4*8);
        const short8 wR1 = *reinterpret_cast<const short8*>(whhb + ((ft     )*16 + r16)*64 + 32 + g4*8);
        const short8 wZ0 = *reinterpret_cast<const short8*>(whhb + ((ft +  4)*16 + r16)*64 + g4*8);
        const short8 wZ1 = *reinterpret_cast<const short8*>(whhb + ((ft +  4)*16 + r16)*64 + 32 + g4*8);
        const short8 wN0 = *reinterpret_cast<const short8*>(whhb + ((ft +  8)*16 + r16)*64 + g4*8);
        const short8 wN1 = *reinterpret_cast<const short8*>(whhb + ((ft +  8)*16 + r16)*64 + 32 + g4*8);
        #pragma unroll
        for (int u = 0; u < 2; ++u) {
            const int seq = u*16 + r16;
            short8 bh0 = ldsfrag(h0b, 128, seq, g4*8);
            short8 bh1 = ldsfrag(h0b, 128, seq, 32 + g4*8);
            floatx4 hR = {0,0,0,0}, hZ = {0,0,0,0}, hN = {0,0,0,0};
            hR = __builtin_amdgcn_mfma_f32_16x16x32_bf16(wR0, bh0, hR, 0, 0, 0);
            hZ = __builtin_amdgcn_mfma_f32_16x16x32_bf16(wZ0, bh0, hZ, 0, 0, 0);
            hN = __builtin_amdgcn_mfma_f32_16x16x32_bf16(wN0, bh0, hN, 0, 0, 0);
            hR = __builtin_amdgcn_mfma_f32_16x16x32_bf16(wR1, bh1, hR, 0, 0, 0);
            hZ = __builtin_amdgcn_mfma_f32_16x16x32_bf16(wZ1, bh1, hZ, 0, 0, 0);
            hN = __builtin_amdgcn_mfma_f32_16x16x32_bf16(wN1, bh1, hN, 0, 0, 0);
            floatx4 hn;
            #pragma unroll
            for (int q = 0; q < 4; ++q) {
                float r = sigm(g1R[u][q] + bihR[q] + hR[q] + bhhR[q]);
                float z = sigm(g1Z[u][q] + bihZ[q] + hZ[q] + bhhZ[q]);
                float n = tanhfast(g1N[u][q] + bihN[q] + r*(hN[q] + bhhN[q]));
                hn[q] = (1.0f - z)*n + z*h0v[u][q];
            }
            unsigned int lo = (unsigned int)f2bf(hn[0]) | ((unsigned int)f2bf(hn[1]) << 16);
            unsigned int hi = (unsigned int)f2bf(hn[2]) | ((unsigned int)f2bf(hn[3]) << 16);
            uint2v vv = {lo, hi};
            int row = 32 + seq;
            int ba = row*128 + fb*2; ba ^= swz(row);
            *reinterpret_cast<uint2v*>(sxb + ba) = vv;
        }
    }
    __syncthreads();   // sxb all 64 rows ready; h0b dead -> h1q writable

    // ---- FC1/FC2 in four 128-feature quarters; FC2 acc[2][4] in registers ----
    const int mt0 = wv*2, mt1 = wv*2 + 1;   // FC2 output ftiles owned by this wave
    floatx4 acc[2][4];
    {
        const floatx4 bA = *reinterpret_cast<const floatx4*>(b2 + mt0*16 + g4*4);
        const floatx4 bB = *reinterpret_cast<const floatx4*>(b2 + mt1*16 + g4*4);
        #pragma unroll
        for (int rt = 0; rt < 4; ++rt) { acc[0][rt] = bA; acc[1][rt] = bB; }
    }

    #pragma unroll
    for (int qq = 0; qq < 4; ++qq) {
        // FC1 quarter qq: global ftiles qq*8 + wv*2 + j -> local cols (wv*2+j)*16
        #pragma unroll
        for (int rt = 0; rt < 4; ++rt) {
            short8 f0 = ldsfrag(sxb, 128, rt*16 + r16, g4*8);
            short8 f1 = ldsfrag(sxb, 128, rt*16 + r16, 32 + g4*8);
            #pragma unroll
            for (int j = 0; j < 2; ++j) {
                int mtg = qq*8 + wv*2 + j;
                int mtl = wv*2 + j;
                const short8 a0 = *reinterpret_cast<const short8*>(w1b + (mtg*16 + r16)*64 + g4*8);
                const short8 a1 = *reinterpret_cast<const short8*>(w1b + (mtg*16 + r16)*64 + 32 + g4*8);
                floatx4 a = *reinterpret_cast<const floatx4*>(b1 + mtg*16 + g4*4);
                a = __builtin_amdgcn_mfma_f32_16x16x32_bf16(a0, f0, a, 0, 0, 0);
                a = __builtin_amdgcn_mfma_f32_16x16x32_bf16(a1, f1, a, 0, 0, 0);
                unsigned int lo = (unsigned int)f2bf(fmaxf(a[0],0.f)) | ((unsigned int)f2bf(fmaxf(a[1],0.f)) << 16);
                unsigned int hi = (unsigned int)f2bf(fmaxf(a[2],0.f)) | ((unsigned int)f2bf(fmaxf(a[3],0.f)) << 16);
                int row = rt*16 + r16;
                int byte = row*256 + (mtl*16 + g4*4)*2; byte ^= swz(row);
                uint2v vv = {lo, hi};
                *reinterpret_cast<uint2v*>(h1q + byte) = vv;
            }
        }
        __syncthreads();   // h1q (this quarter) ready

        // FC2 accumulate over this quarter (4 k-steps)
        {
            const unsigned short* wp0 = w2b + (mt0*16 + r16)*512 + qq*128 + g4*8;
            const unsigned short* wp1 = w2b + (mt1*16 + r16)*512 + qq*128 + g4*8;
            #pragma unroll
            for (int ks = 0; ks < 4; ++ks) {
                const short8 a0 = *reinterpret_cast<const short8*>(wp0 + ks*32);
                const short8 a1 = *reinterpret_cast<const short8*>(wp1 + ks*32);
                #pragma unroll
                for (int rt = 0; rt < 4; ++rt) {
                    short8 bb = ldsfrag(h1q, 256, rt*16 + r16, ks*32 + g4*8);
                    acc[0][rt] = __builtin_amdgcn_mfma_f32_16x16x32_bf16(a0, bb, acc[0][rt], 0, 0, 0);
                    acc[1][rt] = __builtin_amdgcn_mfma_f32_16x16x32_bf16(a1, bb, acc[1][rt], 0, 0, 0);
                }
            }
        }
        __syncthreads();   // h1q reads done -> next quarter may overwrite
    }

    // ---- fused FC3 partial (sxb reads all done -> fc3p writable) ----
    {
        const floatx4 w3a = *reinterpret_cast<const floatx4*>(w3 + mt0*16 + g4*4);
        const floatx4 w3b = *reinterpret_cast<const floatx4*>(w3 + mt1*16 + g4*4);
        #pragma unroll
        for (int rt = 0; rt < 4; ++rt) {
            float p = fmaxf(acc[0][rt][0],0.f)*w3a[0] + fmaxf(acc[0][rt][1],0.f)*w3a[1]
                    + fmaxf(acc[0][rt][2],0.f)*w3a[2] + fmaxf(acc[0][rt][3],0.f)*w3a[3]
                    + fmaxf(acc[1][rt][0],0.f)*w3b[0] + fmaxf(acc[1][rt][1],0.f)*w3b[1]
                    + fmaxf(acc[1][rt][2],0.f)*w3b[2] + fmaxf(acc[1][rt][3],0.f)*w3b[3];
            p += __shfl_xor(p, 16);
            p += __shfl_xor(p, 32);
            if (g4 == 0) fc3p[wv*64 + rt*16 + r16] = p;
        }
    }
    __syncthreads();

    // ---- final: per row, sum 4 wave-partials + b3; write sa (+ out0 gather) ----
    if (tid < 64) {
        float v = b3[0];
        #pragma unroll
        for (int w = 0; w < 4; ++w) v += fc3p[w*64 + tid];
        int t = tid >> 5, sl = tid & 31;
        int gseq = s0 + sl;
        int i = gseq*2 + t;
        sa[i] = v;
        int m = i % 200;
        if (m >= 100) out0[(i/200)*NZ + (m - 100)] = v;
    }
}

// ---------------------------------------------------------------------------
// Critic MFMA: 16 batch rows per block × 64 blocks, 8 waves — unchanged
// ---------------------------------------------------------------------------
__global__ __launch_bounds__(512)
void critic_mfma(const float* __restrict__ x, const float* __restrict__ sa,
                 const unsigned short* __restrict__ cwihb, const unsigned short* __restrict__ cwhhb,
                 const float* __restrict__ cbih, const float* __restrict__ cbhh,
                 const unsigned short* __restrict__ cf1wb, const float* __restrict__ cf1b,
                 const unsigned short* __restrict__ cf2wb, const float* __restrict__ cf2b,
                 const float* __restrict__ cf3w, const float* __restrict__ cf3b,
                 const unsigned short* __restrict__ l1wb, const float* __restrict__ l1b,
                 const unsigned short* __restrict__ l2wb, const float* __restrict__ l2b,
                 const float* __restrict__ l3w, const float* __restrict__ l3b,
                 float* __restrict__ outq)
{
    __shared__ __align__(16) char smem[25600];
    char*  xib = smem;                    // [32 trow][64] bf16 stride 128
    char*  h1b = smem + 4096;             // [16][512] bf16 stride 1024
    char*  h0b = smem + 20480;            // [16][64B] stride 128
    char*  hqb = smem + 22528;            // [16][64B] stride 128
    float* fp  = (float*)(smem + 24576);  // [8][16]
    float* qp  = (float*)(smem + 25088);  // [8][16]

    const int tid  = threadIdx.x;
    const int wv   = tid >> 6;
    const int lane = tid & 63;
    const int r16  = lane & 15;
    const int g4   = lane >> 4;
    const int b0   = blockIdx.x * 16;

    for (int e = tid; e < 2048; e += 512) {
        int trow = e >> 6, k = e & 63;
        int t = trow >> 4, row = trow & 15;
        int b = b0 + row;
        float v = 0.0f;
        if (k < 35) {
            int slot = k / 7, s = k - slot*7;
            int nb = (slot==0)?99:((slot==1)?89:((slot==4)?98:-1));
            if (nb >= 0) v = (s < 6) ? x[((b*NT + t)*NZ + nb)*NS + s]
                                     : sa[b*200 + t*100 + nb];
        }
        int byte = trow*128 + k*2; byte ^= ((trow & 7) << 4);
        *reinterpret_cast<unsigned short*>(xib + byte) = f2bf(v);
    }
    __syncthreads();

    {
        short8 bx0 = ldsfragC(xib, 128, 16 + r16, g4*8);
        short8 bx1 = ldsfragC(xib, 128, 16 + r16, 32 + g4*8);
        #pragma unroll
        for (int j = 0; j < 4; ++j) {
            int mt = wv*4 + j;
            const short8 a0 = *reinterpret_cast<const short8*>(l1wb + (mt*16 + r16)*64 + g4*8);
            const short8 a1 = *reinterpret_cast<const short8*>(l1wb + (mt*16 + r16)*64 + 32 + g4*8);
            floatx4 acc = *reinterpret_cast<const floatx4*>(l1b + mt*16 + g4*4);
            acc = __builtin_amdgcn_mfma_f32_16x16x32_bf16(a0, bx0, acc, 0, 0, 0);
            acc = __builtin_amdgcn_mfma_f32_16x16x32_bf16(a1, bx1, acc, 0, 0, 0);
            unsigned int lo = (unsigned int)f2bf(fmaxf(acc[0],0.f)) | ((unsigned int)f2bf(fmaxf(acc[1],0.f)) << 16);
            unsigned int hi = (unsigned int)f2bf(fmaxf(acc[2],0.f)) | ((unsigned int)f2bf(fmaxf(acc[3],0.f)) << 16);
            int byte = r16*1024 + (mt*16 + g4*4)*2; byte ^= ((r16 & 7) << 4);
            uint2v vv = {lo, hi};
            *reinterpret_cast<uint2v*>(h1b + byte) = vv;
        }
    }
    __syncthreads();

    {
        int mt0 = wv*2, mt1 = wv*2 + 1;
        floatx4 acc0 = *reinterpret_cast<const floatx4*>(l2b + mt0*16 + g4*4);
        floatx4 acc1 = *reinterpret_cast<const floatx4*>(l2b + mt1*16 + g4*4);
        const unsigned short* wp0 = l2wb + (mt0*16 + r16)*512 + g4*8;
        const unsigned short* wp1 = l2wb + (mt1*16 + r16)*512 + g4*8;
        for (int ks = 0; ks < 16; ++ks) {
            short8 bb = ldsfragC(h1b, 1024, r16, ks*32 + g4*8);
            const short8 a0 = *reinterpret_cast<const short8*>(wp0 + ks*32);
            const short8 a1 = *reinterpret_cast<const short8*>(wp1 + ks*32);
            acc0 = __builtin_amdgcn_mfma_f32_16x16x32_bf16(a0, bb, acc0, 0, 0, 0);
            acc1 = __builtin_amdgcn_mfma_f32_16x16x32_bf16(a1, bb, acc1, 0, 0, 0);
        }
        const floatx4 w0 = *reinterpret_cast<const floatx4*>(l3w + mt0*16 + g4*4);
        const floatx4 w1 = *reinterpret_cast<const floatx4*>(l3w + mt1*16 + g4*4);
        float p = fmaxf(acc0[0],0.f)*w0[0] + fmaxf(acc0[1],0.f)*w0[1]
                + fmaxf(acc0[2],0.f)*w0[2] + fmaxf(acc0[3],0.f)*w0[3]
                + fmaxf(acc1[0],0.f)*w1[0] + fmaxf(acc1[1],0.f)*w1[1]
                + fmaxf(acc1[2],0.f)*w1[2] + fmaxf(acc1[3],0.f)*w1[3];
        p += __shfl_xor(p, 16);
        p += __shfl_xor(p, 32);
        if (g4 == 0) fp[wv*16 + r16] = p;
    }
    __syncthreads();

    floatx4 h0r = {0,0,0,0};
    floatx4 gR1 = {0,0,0,0}, gZ1 = {0,0,0,0}, gN1 = {0,0,0,0};
    floatx4 bihR, bihZ, bihN, bhhR, bhhZ, bhhN;
    if (wv < 2) {
        const int hf = wv;
        const int fb = hf*16 + g4*4;
        bihR = *reinterpret_cast<const floatx4*>(cbih + fb);
        bihZ = *reinterpret_cast<const floatx4*>(cbih + 32 + fb);
        bihN = *reinterpret_cast<const floatx4*>(cbih + 64 + fb);
        bhhR = *reinterpret_cast<const floatx4*>(cbhh + fb);
        bhhZ = *reinterpret_cast<const floatx4*>(cbhh + 32 + fb);
        bhhN = *reinterpret_cast<const floatx4*>(cbhh + 64 + fb);
        short8 bx0 = ldsfragC(xib, 128, r16, g4*8);
        short8 bx1 = ldsfragC(xib, 128, r16, 32 + g4*8);
        short8 cx0 = ldsfragC(xib, 128, 16 + r16, g4*8);
        short8 cx1 = ldsfragC(xib, 128, 16 + r16, 32 + g4*8);
        floatx4 gR0 = {0,0,0,0}, gZ0 = {0,0,0,0}, gN0 = {0,0,0,0};
        #pragma unroll
        for (int p = 0; p < 2; ++p) {
            const short8 aR = *reinterpret_cast<const short8*>(cwihb + ((hf    )*16 + r16)*64 + p*32 + g4*8);
            const short8 aZ = *reinterpret_cast<const short8*>(cwihb + ((2+hf  )*16 + r16)*64 + p*32 + g4*8);
            const short8 aN = *reinterpret_cast<const short8*>(cwihb + ((4+hf  )*16 + r16)*64 + p*32 + g4*8);
            short8 b0f = p ? bx1 : bx0;
            short8 b1f = p ? cx1 : cx0;
            gR0 = __builtin_amdgcn_mfma_f32_16x16x32_bf16(aR, b0f, gR0, 0, 0, 0);
            gZ0 = __builtin_amdgcn_mfma_f32_16x16x32_bf16(aZ, b0f, gZ0, 0, 0, 0);
            gN0 = __builtin_amdgcn_mfma_f32_16x16x32_bf16(aN, b0f, gN0, 0, 0, 0);
            gR1 = __builtin_amdgcn_mfma_f32_16x16x32_bf16(aR, b1f, gR1, 0, 0, 0);
            gZ1 = __builtin_amdgcn_mfma_f32_16x16x32_bf16(aZ, b1f, gZ1, 0, 0, 0);
            gN1 = __builtin_amdgcn_mfma_f32_16x16x32_bf16(aN, b1f, gN1, 0, 0, 0);
        }
        #pragma unroll
        for (int q = 0; q < 4; ++q) {
            float r = sigm(gR0[q] + bihR[q] + bhhR[q]);
            float z = sigm(gZ0[q] + bihZ[q] + bhhZ[q]);
            float n = tanhfast(gN0[q] + bihN[q] + r*bhhN[q]);
            h0r[q] = (1.0f - z)*n;
        }
        unsigned int lo = (unsigned int)f2bf(h0r[0]) | ((unsigned int)f2bf(h0r[1]) << 16);
        unsigned int hi = (unsigned int)f2bf(h0r[2]) | ((unsigned int)f2bf(h0r[3]) << 16);
        uint2v vv = {lo, hi};
        int byte = r16*128 + fb*2; byte ^= ((r16 & 7) << 4);
        *reinterpret_cast<uint2v*>(h0b + byte) = vv;
    }
    __syncthreads();
    if (wv < 2) {
        const int hf = wv;
        const int fb = hf*16 + g4*4;
        short8 bh = ldsfragC(h0b, 128, r16, g4*8);
        const short8 aR = *reinterpret_cast<const short8*>(cwhhb + ((hf    )*16 + r16)*32 + g4*8);
        const short8 aZ = *reinterpret_cast<const short8*>(cwhhb + ((2+hf  )*16 + r16)*32 + g4*8);
        const short8 aN = *reinterpret_cast<const short8*>(cwhhb + ((4+hf  )*16 + r16)*32 + g4*8);
        floatx4 hR = {0,0,0,0}, hZ = {0,0,0,0}, hN = {0,0,0,0};
        hR = __builtin_amdgcn_mfma_f32_16x16x32_bf16(aR, bh, hR, 0, 0, 0);
        hZ = __builtin_amdgcn_mfma_f32_16x16x32_bf16(aZ, bh, hZ, 0, 0, 0);
        hN = __builtin_amdgcn_mfma_f32_16x16x32_bf16(aN, bh, hN, 0, 0, 0);
        floatx4 hn;
        #pragma unroll
        for (int q = 0; q < 4; ++q) {
            float r = sigm(gR1[q] + bihR[q] + hR[q] + bhhR[q]);
            float z = sigm(gZ1[q] + bihZ[q] + hZ[q] + bhhZ[q]);
            float n = tanhfast(gN1[q] + bihN[q] + r*(hN[q] + bhhN[q]));
            hn[q] = (1.0f - z)*n + z*h0r[q];
        }
        unsigned int lo = (unsigned int)f2bf(hn[0]) | ((unsigned int)f2bf(hn[1]) << 16);
        unsigned int hi = (unsigned int)f2bf(hn[2]) | ((unsigned int)f2bf(hn[3]) << 16);
        uint2v vv = {lo, hi};
        int byte = r16*128 + fb*2; byte ^= ((r16 & 7) << 4);
        *reinterpret_cast<uint2v*>(hqb + byte) = vv;
    }
    __syncthreads();

    {
        short8 bq = ldsfragC(hqb, 128, r16, g4*8);
        #pragma unroll
        for (int j = 0; j < 4; ++j) {
            int mt = wv*4 + j;
            const short8 a = *reinterpret_cast<const short8*>(cf1wb + (mt*16 + r16)*32 + g4*8);
            floatx4 acc = *reinterpret_cast<const floatx4*>(cf1b + mt*16 + g4*4);
            acc = __builtin_amdgcn_mfma_f32_16x16x32_bf16(a, bq, acc, 0, 0, 0);
            unsigned int lo = (unsigned int)f2bf(fmaxf(acc[0],0.f)) | ((unsigned int)f2bf(fmaxf(acc[1],0.f)) << 16);
            unsigned int hi = (unsigned int)f2bf(fmaxf(acc[2],0.f)) | ((unsigned int)f2bf(fmaxf(acc[3],0.f)) << 16);
            int byte = r16*1024 + (mt*16 + g4*4)*2; byte ^= ((r16 & 7) << 4);
            uint2v vv = {lo, hi};
            *reinterpret_cast<uint2v*>(h1b + byte) = vv;
        }
    }
    __syncthreads();

    {
        int mt0 = wv*2, mt1 = wv*2 + 1;
        floatx4 acc0 = *reinterpret_cast<const floatx4*>(cf2b + mt0*16 + g4*4);
        floatx4 acc1 = *reinterpret_cast<const floatx4*>(cf2b + mt1*16 + g4*4);
        const unsigned short* wp0 = cf2wb + (mt0*16 + r16)*512 + g4*8;
        const unsigned short* wp1 = cf2wb + (mt1*16 + r16)*512 + g4*8;
        for (int ks = 0; ks < 16; ++ks) {
            short8 bb = ldsfragC(h1b, 1024, r16, ks*32 + g4*8);
            const short8 a0 = *reinterpret_cast<const short8*>(wp0 + ks*32);
            const short8 a1 = *reinterpret_cast<const short8*>(wp1 + ks*32);
            acc0 = __builtin_amdgcn_mfma_f32_16x16x32_bf16(a0, bb, acc0, 0, 0, 0);
            acc1 = __builtin_amdgcn_mfma_f32_16x16x32_bf16(a1, bb, acc1, 0, 0, 0);
        }
        const floatx4 w0 = *reinterpret_cast<const floatx4*>(cf3w + mt0*16 + g4*4);
        const floatx4 w1 = *reinterpret_cast<const floatx4*>(cf3w + mt1*16 + g4*4);
        float p = fmaxf(acc0[0],0.f)*w0[0] + fmaxf(acc0[1],0.f)*w0[1]
                + fmaxf(acc0[2],0.f)*w0[2] + fmaxf(acc0[3],0.f)*w0[3]
                + fmaxf(acc1[0],0.f)*w1[0] + fmaxf(acc1[1],0.f)*w1[1]
                + fmaxf(acc1[2],0.f)*w1[2] + fmaxf(acc1[3],0.f)*w1[3];
        p += __shfl_xor(p, 16);
        p += __shfl_xor(p, 32);
        if (g4 == 0) qp[wv*16 + r16] = p;
    }
    __syncthreads();

    if (tid < 16) {
        float f = l3b[0], qz = cf3b[0];
        #pragma unroll
        for (int w = 0; w < 8; ++w) { f += fp[w*16 + tid]; qz += qp[w*16 + tid]; }
        outq[b0 + tid] = f + qz;
    }
}

extern "C" void kernel_launch(void* const* d_in, const int* in_sizes, int n_in,
                              void* d_out, int out_size, void* d_ws, size_t ws_size,
                              hipStream_t stream)
{
    (void)in_sizes; (void)n_in; (void)out_size; (void)ws_size;
    const float* x     = (const float*)d_in[0];
    const float* a_wih = (const float*)d_in[1];
    const float* a_whh = (const float*)d_in[2];
    const float* a_bih = (const float*)d_in[3];
    const float* a_bhh = (const float*)d_in[4];
    const float* a1w   = (const float*)d_in[5];
    const float* a1b   = (const float*)d_in[6];
    const float* a2w   = (const float*)d_in[7];
    const float* a2b   = (const float*)d_in[8];
    const float* a3w   = (const float*)d_in[9];
    const float* a3b   = (const float*)d_in[10];
    const float* cwih  = (const float*)d_in[11];
    const float* cwhh  = (const float*)d_in[12];
    const float* cbih  = (const float*)d_in[13];
    const float* cbhh  = (const float*)d_in[14];
    const float* cf1w  = (const float*)d_in[15];
    const float* cf1b  = (const float*)d_in[16];
    const float* cf2w  = (const float*)d_in[17];
    const float* cf2b  = (const float*)d_in[18];
    const float* cf3w  = (const float*)d_in[19];
    const float* cf3b  = (const float*)d_in[20];
    const float* l1w   = (const float*)d_in[21];
    const float* l1b   = (const float*)d_in[22];
    const float* l2w   = (const float*)d_in[23];
    const float* l2b   = (const float*)d_in[24];
    const float* l3w   = (const float*)d_in[25];
    const float* l3b   = (const float*)d_in[26];

    float* sa = (float*)d_ws;
    unsigned short* wihb  = (unsigned short*)((char*)d_ws + WS_WIHB);
    unsigned short* whhb  = (unsigned short*)((char*)d_ws + WS_WHHB);
    unsigned short* w1b   = (unsigned short*)((char*)d_ws + WS_W1B);
    unsigned short* w2b   = (unsigned short*)((char*)d_ws + WS_W2B);
    unsigned short* l1wb  = (unsigned short*)((char*)d_ws + WS_L1WB);
    unsigned short* l2wb  = (unsigned short*)((char*)d_ws + WS_L2WB);
    unsigned short* cf1wb = (unsigned short*)((char*)d_ws + WS_CF1WB);
    unsigned short* cf2wb = (unsigned short*)((char*)d_ws + WS_CF2WB);
    unsigned short* cwihb = (unsigned short*)((char*)d_ws + WS_CWIHB);
    unsigned short* cwhhb = (unsigned short*)((char*)d_ws + WS_CWHHB);
    float* out0 = (float*)d_out;
    float* outq = (float*)d_out + NB*NZ;

    hipLaunchKernelGGL(prep_kernel, dim3((PREP_N + 255)/256), dim3(256), 0, stream,
                       a_wih, a_whh, a1w, a2w, l1w, l2w, cf1w, cf2w, cwih, cwhh,
                       wihb, whhb, w1b, w2b, l1wb, l2wb, cf1wb, cf2wb, cwihb, cwhhb);
    hipLaunchKernelGGL(actor_mfma, dim3(NSEQ/32), dim3(256), 0, stream,
                       x, wihb, whhb, a_bih, a_bhh, w1b, a1b, w2b, a2b, a3w, a3b, sa, out0);
    hipLaunchKernelGGL(critic_mfma, dim3(NB/16), dim3(512), 0, stream,
                       x, sa, cwihb, cwhhb, cbih, cbhh, cf1wb, cf1b, cf2wb, cf2b, cf3w, cf3b,
                       l1wb, l1b, l2wb, l2b, l3w, l3b, outq);
}

// Round 11
// 131.761 us; speedup vs baseline: 1.4206x; 1.1611x over previous
//
#include <hip/hip_runtime.h>
#include <hip/hip_bf16.h>

#define NB 1024      // batch
#define NT 2         // time
#define NZ 100       // zones
#define NS 6         // state dim
#define NSEQ (NZ*NB) // actor sequences

typedef short short8 __attribute__((ext_vector_type(8)));
typedef float floatx4 __attribute__((ext_vector_type(4)));
typedef unsigned int uint2v __attribute__((ext_vector_type(2)));

__device__ __forceinline__ float sigm(float v)     { return 1.0f/(1.0f + __expf(-v)); }
__device__ __forceinline__ float tanhfast(float v) { float t = __expf(2.0f*v); return 1.0f - 2.0f/(t + 1.0f); }
__device__ __forceinline__ unsigned short f2bf(float f) {
    __hip_bfloat16 h = __float2bfloat16(f);
    return *reinterpret_cast<unsigned short*>(&h);
}

// ---------------- workspace byte offsets ----------------
#define WS_WIHB   819200                     // [192][32] bf16 (K 6->32)
#define WS_WHHB   (WS_WIHB + 192*32*2)       // [192][64]
#define WS_W1B    (WS_WHHB + 192*64*2)       // [512][64]
#define WS_W2B    (WS_W1B + 512*64*2)        // [128][512]
#define WS_L1WB   (WS_W2B + 128*512*2)       // [512][64]  (K 35->64)
#define WS_L2WB   (WS_L1WB + 512*64*2)       // [256][512]
#define WS_CF1WB  (WS_L2WB + 256*512*2)      // [512][32]
#define WS_CF2WB  (WS_CF1WB + 512*32*2)      // [256][512]
#define WS_CWIHB  (WS_CF2WB + 256*512*2)     // [96][64]   (K 35->64)
#define WS_CWHHB  (WS_CWIHB + 96*64*2)       // [96][32]
// end = WS_CWHHB + 96*32*2 = 1693696 B

#define PREP_N (116736 + 32768 + 131072 + 16384 + 131072 + 6144 + 3072)  // 437248

__global__ __launch_bounds__(256)
void prep_kernel(const float* __restrict__ wih, const float* __restrict__ whh,
                 const float* __restrict__ w1,  const float* __restrict__ w2,
                 const float* __restrict__ l1w, const float* __restrict__ l2w,
                 const float* __restrict__ cf1w, const float* __restrict__ cf2w,
                 const float* __restrict__ cwih, const float* __restrict__ cwhh,
                 unsigned short* wihb, unsigned short* whhb,
                 unsigned short* w1b,  unsigned short* w2b,
                 unsigned short* l1wb, unsigned short* l2wb,
                 unsigned short* cf1wb, unsigned short* cf2wb,
                 unsigned short* cwihb, unsigned short* cwhhb)
{
    int e = blockIdx.x*256 + threadIdx.x;
    if (e < 6144) {
        int g = e >> 5, k = e & 31;
        wihb[e] = f2bf(k < 6 ? wih[g*6 + k] : 0.0f);
    } else if (e < 18432) {
        int i = e - 6144;  whhb[i] = f2bf(whh[i]);
    } else if (e < 51200) {
        int i = e - 18432; w1b[i] = f2bf(w1[i]);
    } else if (e < 116736) {
        int i = e - 51200; w2b[i] = f2bf(w2[i]);
    } else if (e < 149504) {                    // l1wb [512][64] from [512][35]
        int i = e - 116736; int o = i >> 6, k = i & 63;
        l1wb[i] = f2bf(k < 35 ? l1w[o*35 + k] : 0.0f);
    } else if (e < 280576) {                    // l2wb copy
        int i = e - 149504; l2wb[i] = f2bf(l2w[i]);
    } else if (e < 296960) {                    // cf1wb copy
        int i = e - 280576; cf1wb[i] = f2bf(cf1w[i]);
    } else if (e < 428032) {                    // cf2wb copy
        int i = e - 296960; cf2wb[i] = f2bf(cf2w[i]);
    } else if (e < 434176) {                    // cwihb [96][64] from [96][35]
        int i = e - 428032; int o = i >> 6, k = i & 63;
        cwihb[i] = f2bf(k < 35 ? cwih[o*35 + k] : 0.0f);
    } else if (e < PREP_N) {                    // cwhhb copy
        int i = e - 434176; cwhhb[i] = f2bf(cwhh[i]);
    }
}

// 1-bit XOR swizzle (proven: 2-way row aliasing is free; R10's 2-bit variant aliased)
__device__ __forceinline__ int swz(int r) { return (r & 7) << 4; }

__device__ __forceinline__ short8 ldsfrag(const char* base, int rowstride, int r, int k0) {
    int byte = r*rowstride + k0*2;
    byte ^= swz(r);
    return *reinterpret_cast<const short8*>(base + byte);
}

// build GI B-fragment directly from global x; k>=6 pairs with zero A-columns
__device__ __forceinline__ short8 xfrag(const float* __restrict__ xp) {
    float2 a  = *reinterpret_cast<const float2*>(xp);
    float2 b2 = *reinterpret_cast<const float2*>(xp + 2);
    float2 c  = *reinterpret_cast<const float2*>(xp + 4);
    short8 f;
    f[0] = (short)f2bf(a.x);  f[1] = (short)f2bf(a.y);
    f[2] = (short)f2bf(b2.x); f[3] = (short)f2bf(b2.y);
    f[4] = (short)f2bf(c.x);  f[5] = (short)f2bf(c.y);
    f[6] = 0; f[7] = 0;
    return f;
}

// ---------------------------------------------------------------------------
// Actor: 32 seqs (64 rows, row = t*32+sl) per 256-thread block (4 waves).
// LDS 40960 B. FC1/FC2 in two 256-feature halves; FC2 acc[2][4] in registers;
// FC1 sxb fragments hoisted (loaded once). 6 barriers/block. GH reads sxb
// rows 0..31 directly (t0 outputs) - no separate h0 buffer.
// ---------------------------------------------------------------------------
__global__ __launch_bounds__(256)
void actor_mfma(const float* __restrict__ x,
                const unsigned short* __restrict__ wihb, const unsigned short* __restrict__ whhb,
                const float* __restrict__ bih, const float* __restrict__ bhh,
                const unsigned short* __restrict__ w1b, const float* __restrict__ b1,
                const unsigned short* __restrict__ w2b, const float* __restrict__ b2,
                const float* __restrict__ w3, const float* __restrict__ b3,
                float* __restrict__ sa, float* __restrict__ out0)
{
    __shared__ __align__(16) char smem[40960];
    char*  sxb  = smem;              // [64 rows][64] bf16 stride 128 (GRU out)
    float* fc3p = (float*)smem;      // [4][64] f32 (aliases sxb; written post-FC2)
    char*  h1b  = smem + 8192;       // [64 rows][256 feats] bf16 stride 512 (half)

    const int tid  = threadIdx.x;
    const int wv   = tid >> 6;       // 0..3 = feature-triple ft
    const int lane = tid & 63;
    const int r16  = lane & 15;
    const int g4   = lane >> 4;
    const int ft   = wv;
    const int s0   = blockIdx.x * 32;
    const int zz   = s0 >> 10;
    const int b0   = s0 & 1023;

    const int fb = ft*16 + g4*4;
    const floatx4 bihR = *reinterpret_cast<const floatx4*>(bih + fb);
    const floatx4 bihZ = *reinterpret_cast<const floatx4*>(bih + 64 + fb);
    const floatx4 bihN = *reinterpret_cast<const floatx4*>(bih + 128 + fb);
    const floatx4 bhhR = *reinterpret_cast<const floatx4*>(bhh + fb);
    const floatx4 bhhZ = *reinterpret_cast<const floatx4*>(bhh + 64 + fb);
    const floatx4 bhhN = *reinterpret_cast<const floatx4*>(bhh + 128 + fb);

    floatx4 h0v[2];
    floatx4 g1R[2], g1Z[2], g1N[2];

    // ---- GI (t0+t1), GRU t0 in-register; x direct from global ----
    {
        const short8 aR = *reinterpret_cast<const short8*>(wihb + ((ft     )*16 + r16)*32 + g4*8);
        const short8 aZ = *reinterpret_cast<const short8*>(wihb + ((ft +  4)*16 + r16)*32 + g4*8);
        const short8 aN = *reinterpret_cast<const short8*>(wihb + ((ft +  8)*16 + r16)*32 + g4*8);
        #pragma unroll
        for (int u = 0; u < 2; ++u) {
            const int seq = u*16 + r16;
            const float* xrow = x + (((b0 + seq)*NT)*NZ + zz)*NS;
            short8 bx0 = xfrag(xrow);            // t=0
            short8 bx1 = xfrag(xrow + NZ*NS);    // t=1
            floatx4 gR = {0,0,0,0}, gZ = {0,0,0,0}, gN = {0,0,0,0};
            gR = __builtin_amdgcn_mfma_f32_16x16x32_bf16(aR, bx0, gR, 0, 0, 0);
            gZ = __builtin_amdgcn_mfma_f32_16x16x32_bf16(aZ, bx0, gZ, 0, 0, 0);
            gN = __builtin_amdgcn_mfma_f32_16x16x32_bf16(aN, bx0, gN, 0, 0, 0);
            floatx4 tR = {0,0,0,0}, tZ = {0,0,0,0}, tN = {0,0,0,0};
            tR = __builtin_amdgcn_mfma_f32_16x16x32_bf16(aR, bx1, tR, 0, 0, 0);
            tZ = __builtin_amdgcn_mfma_f32_16x16x32_bf16(aZ, bx1, tZ, 0, 0, 0);
            tN = __builtin_amdgcn_mfma_f32_16x16x32_bf16(aN, bx1, tN, 0, 0, 0);
            g1R[u] = tR; g1Z[u] = tZ; g1N[u] = tN;
            floatx4 hh;
            #pragma unroll
            for (int q = 0; q < 4; ++q) {
                float r = sigm(gR[q] + bihR[q] + bhhR[q]);
                float z = sigm(gZ[q] + bihZ[q] + bhhZ[q]);
                float n = tanhfast(gN[q] + bihN[q] + r*bhhN[q]);
                hh[q] = (1.0f - z)*n;
            }
            h0v[u] = hh;
            unsigned int lo = (unsigned int)f2bf(hh[0]) | ((unsigned int)f2bf(hh[1]) << 16);
            unsigned int hi = (unsigned int)f2bf(hh[2]) | ((unsigned int)f2bf(hh[3]) << 16);
            uint2v vv = {lo, hi};
            int ba = seq*128 + fb*2; ba ^= swz(seq);
            *reinterpret_cast<uint2v*>(sxb + ba) = vv;    // t0 GRU output (row=seq) = h0
        }
    }
    __syncthreads();   // sxb rows 0..31 (h0) ready

    // ---- GH + GRU t1 in-register (B-operand = sxb rows 0..31) ----
    {
        const short8 wR0 = *reinterpret_cast<const short8*>(whhb + ((ft     )*16 + r16)*64 + g4*8);
        const short8 wR1 = *reinterpret_cast<const short8*>(whhb + ((ft     )*16 + r16)*64 + 32 + g4*8);
        const short8 wZ0 = *reinterpret_cast<const short8*>(whhb + ((ft +  4)*16 + r16)*64 + g4*8);
        const short8 wZ1 = *reinterpret_cast<const short8*>(whhb + ((ft +  4)*16 + r16)*64 + 32 + g4*8);
        const short8 wN0 = *reinterpret_cast<const short8*>(whhb + ((ft +  8)*16 + r16)*64 + g4*8);
        const short8 wN1 = *reinterpret_cast<const short8*>(whhb + ((ft +  8)*16 + r16)*64 + 32 + g4*8);
        #pragma unroll
        for (int u = 0; u < 2; ++u) {
            const int seq = u*16 + r16;
            short8 bh0 = ldsfrag(sxb, 128, seq, g4*8);
            short8 bh1 = ldsfrag(sxb, 128, seq, 32 + g4*8);
            floatx4 hR = {0,0,0,0}, hZ = {0,0,0,0}, hN = {0,0,0,0};
            hR = __builtin_amdgcn_mfma_f32_16x16x32_bf16(wR0, bh0, hR, 0, 0, 0);
            hZ = __builtin_amdgcn_mfma_f32_16x16x32_bf16(wZ0, bh0, hZ, 0, 0, 0);
            hN = __builtin_amdgcn_mfma_f32_16x16x32_bf16(wN0, bh0, hN, 0, 0, 0);
            hR = __builtin_amdgcn_mfma_f32_16x16x32_bf16(wR1, bh1, hR, 0, 0, 0);
            hZ = __builtin_amdgcn_mfma_f32_16x16x32_bf16(wZ1, bh1, hZ, 0, 0, 0);
            hN = __builtin_amdgcn_mfma_f32_16x16x32_bf16(wN1, bh1, hN, 0, 0, 0);
            floatx4 hn;
            #pragma unroll
            for (int q = 0; q < 4; ++q) {
                float r = sigm(g1R[u][q] + bihR[q] + hR[q] + bhhR[q]);
                float z = sigm(g1Z[u][q] + bihZ[q] + hZ[q] + bhhZ[q]);
                float n = tanhfast(g1N[u][q] + bihN[q] + r*(hN[q] + bhhN[q]));
                hn[q] = (1.0f - z)*n + z*h0v[u][q];
            }
            unsigned int lo = (unsigned int)f2bf(hn[0]) | ((unsigned int)f2bf(hn[1]) << 16);
            unsigned int hi = (unsigned int)f2bf(hn[2]) | ((unsigned int)f2bf(hn[3]) << 16);
            uint2v vv = {lo, hi};
            int row = 32 + seq;
            int ba = row*128 + fb*2; ba ^= swz(row);
            *reinterpret_cast<uint2v*>(sxb + ba) = vv;
        }
    }
    __syncthreads();   // sxb all 64 rows ready

    // ---- hoisted FC1 B-fragments: load once, reused across both halves ----
    short8 fr[4][2];
    #pragma unroll
    for (int rt = 0; rt < 4; ++rt) {
        fr[rt][0] = ldsfrag(sxb, 128, rt*16 + r16, g4*8);
        fr[rt][1] = ldsfrag(sxb, 128, rt*16 + r16, 32 + g4*8);
    }

    // ---- FC1/FC2 in two 256-feature halves; FC2 acc[2][4] in registers ----
    const int mt0 = wv*2, mt1 = wv*2 + 1;   // FC2 output ftiles owned by this wave
    floatx4 acc[2][4];
    {
        const floatx4 bA = *reinterpret_cast<const floatx4*>(b2 + mt0*16 + g4*4);
        const floatx4 bB = *reinterpret_cast<const floatx4*>(b2 + mt1*16 + g4*4);
        #pragma unroll
        for (int rt = 0; rt < 4; ++rt) { acc[0][rt] = bA; acc[1][rt] = bB; }
    }

    #pragma unroll
    for (int h = 0; h < 2; ++h) {
        // FC1 half h: global ftiles h*16 + wv*4 + j (wave owns 4 ftiles)
        #pragma unroll
        for (int j = 0; j < 4; ++j) {
            int mtg = h*16 + wv*4 + j;
            int mtl = wv*4 + j;            // local col tile in h1b (0..15)
            const short8 a0 = *reinterpret_cast<const short8*>(w1b + (mtg*16 + r16)*64 + g4*8);
            const short8 a1 = *reinterpret_cast<const short8*>(w1b + (mtg*16 + r16)*64 + 32 + g4*8);
            const floatx4 bias = *reinterpret_cast<const floatx4*>(b1 + mtg*16 + g4*4);
            #pragma unroll
            for (int rt = 0; rt < 4; ++rt) {
                floatx4 a = bias;
                a = __builtin_amdgcn_mfma_f32_16x16x32_bf16(a0, fr[rt][0], a, 0, 0, 0);
                a = __builtin_amdgcn_mfma_f32_16x16x32_bf16(a1, fr[rt][1], a, 0, 0, 0);
                unsigned int lo = (unsigned int)f2bf(fmaxf(a[0],0.f)) | ((unsigned int)f2bf(fmaxf(a[1],0.f)) << 16);
                unsigned int hi = (unsigned int)f2bf(fmaxf(a[2],0.f)) | ((unsigned int)f2bf(fmaxf(a[3],0.f)) << 16);
                int row = rt*16 + r16;
                int byte = row*512 + (mtl*16 + g4*4)*2; byte ^= swz(row);
                uint2v vv = {lo, hi};
                *reinterpret_cast<uint2v*>(h1b + byte) = vv;
            }
        }
        __syncthreads();   // h1b (this half) ready

        // FC2 accumulate over this half's 256 features (8 k-steps)
        {
            const unsigned short* wp0 = w2b + (mt0*16 + r16)*512 + h*256 + g4*8;
            const unsigned short* wp1 = w2b + (mt1*16 + r16)*512 + h*256 + g4*8;
            #pragma unroll
            for (int ks = 0; ks < 8; ++ks) {
                const short8 a0 = *reinterpret_cast<const short8*>(wp0 + ks*32);
                const short8 a1 = *reinterpret_cast<const short8*>(wp1 + ks*32);
                #pragma unroll
                for (int rt = 0; rt < 4; ++rt) {
                    short8 bb = ldsfrag(h1b, 512, rt*16 + r16, ks*32 + g4*8);
                    acc[0][rt] = __builtin_amdgcn_mfma_f32_16x16x32_bf16(a0, bb, acc[0][rt], 0, 0, 0);
                    acc[1][rt] = __builtin_amdgcn_mfma_f32_16x16x32_bf16(a1, bb, acc[1][rt], 0, 0, 0);
                }
            }
        }
        if (h == 0) __syncthreads();   // h1b reads done -> half 1 may overwrite
    }

    // ---- fused FC3 partial (fc3p region disjoint from h1b; sxb reads long done) ----
    {
        const floatx4 w3a = *reinterpret_cast<const floatx4*>(w3 + mt0*16 + g4*4);
        const floatx4 w3b = *reinterpret_cast<const floatx4*>(w3 + mt1*16 + g4*4);
        #pragma unroll
        for (int rt = 0; rt < 4; ++rt) {
            float p = fmaxf(acc[0][rt][0],0.f)*w3a[0] + fmaxf(acc[0][rt][1],0.f)*w3a[1]
                    + fmaxf(acc[0][rt][2],0.f)*w3a[2] + fmaxf(acc[0][rt][3],0.f)*w3a[3]
                    + fmaxf(acc[1][rt][0],0.f)*w3b[0] + fmaxf(acc[1][rt][1],0.f)*w3b[1]
                    + fmaxf(acc[1][rt][2],0.f)*w3b[2] + fmaxf(acc[1][rt][3],0.f)*w3b[3];
            p += __shfl_xor(p, 16);
            p += __shfl_xor(p, 32);
            if (g4 == 0) fc3p[wv*64 + rt*16 + r16] = p;
        }
    }
    __syncthreads();

    // ---- final: per row, sum 4 wave-partials + b3; write sa (+ out0 gather) ----
    if (tid < 64) {
        float v = b3[0];
        #pragma unroll
        for (int w = 0; w < 4; ++w) v += fc3p[w*64 + tid];
        int t = tid >> 5, sl = tid & 31;
        int gseq = s0 + sl;
        int i = gseq*2 + t;
        sa[i] = v;
        int m = i % 200;
        if (m >= 100) out0[(i/200)*NZ + (m - 100)] = v;
    }
}

// ---------------------------------------------------------------------------
// Critic MFMA: 16 batch rows per block × 64 blocks, 8 waves — unchanged
// ---------------------------------------------------------------------------
__global__ __launch_bounds__(512)
void critic_mfma(const float* __restrict__ x, const float* __restrict__ sa,
                 const unsigned short* __restrict__ cwihb, const unsigned short* __restrict__ cwhhb,
                 const float* __restrict__ cbih, const float* __restrict__ cbhh,
                 const unsigned short* __restrict__ cf1wb, const float* __restrict__ cf1b,
                 const unsigned short* __restrict__ cf2wb, const float* __restrict__ cf2b,
                 const float* __restrict__ cf3w, const float* __restrict__ cf3b,
                 const unsigned short* __restrict__ l1wb, const float* __restrict__ l1b,
                 const unsigned short* __restrict__ l2wb, const float* __restrict__ l2b,
                 const float* __restrict__ l3w, const float* __restrict__ l3b,
                 float* __restrict__ outq)
{
    __shared__ __align__(16) char smem[25600];
    char*  xib = smem;                    // [32 trow][64] bf16 stride 128
    char*  h1b = smem + 4096;             // [16][512] bf16 stride 1024
    char*  h0b = smem + 20480;            // [16][64B] stride 128
    char*  hqb = smem + 22528;            // [16][64B] stride 128
    float* fp  = (float*)(smem + 24576);  // [8][16]
    float* qp  = (float*)(smem + 25088);  // [8][16]

    const int tid  = threadIdx.x;
    const int wv   = tid >> 6;
    const int lane = tid & 63;
    const int r16  = lane & 15;
    const int g4   = lane >> 4;
    const int b0   = blockIdx.x * 16;

    for (int e = tid; e < 2048; e += 512) {
        int trow = e >> 6, k = e & 63;
        int t = trow >> 4, row = trow & 15;
        int b = b0 + row;
        float v = 0.0f;
        if (k < 35) {
            int slot = k / 7, s = k - slot*7;
            int nb = (slot==0)?99:((slot==1)?89:((slot==4)?98:-1));
            if (nb >= 0) v = (s < 6) ? x[((b*NT + t)*NZ + nb)*NS + s]
                                     : sa[b*200 + t*100 + nb];
        }
        int byte = trow*128 + k*2; byte ^= ((trow & 7) << 4);
        *reinterpret_cast<unsigned short*>(xib + byte) = f2bf(v);
    }
    __syncthreads();

    {
        short8 bx0 = ldsfrag(xib, 128, 16 + r16, g4*8);
        short8 bx1 = ldsfrag(xib, 128, 16 + r16, 32 + g4*8);
        #pragma unroll
        for (int j = 0; j < 4; ++j) {
            int mt = wv*4 + j;
            const short8 a0 = *reinterpret_cast<const short8*>(l1wb + (mt*16 + r16)*64 + g4*8);
            const short8 a1 = *reinterpret_cast<const short8*>(l1wb + (mt*16 + r16)*64 + 32 + g4*8);
            floatx4 acc = *reinterpret_cast<const floatx4*>(l1b + mt*16 + g4*4);
            acc = __builtin_amdgcn_mfma_f32_16x16x32_bf16(a0, bx0, acc, 0, 0, 0);
            acc = __builtin_amdgcn_mfma_f32_16x16x32_bf16(a1, bx1, acc, 0, 0, 0);
            unsigned int lo = (unsigned int)f2bf(fmaxf(acc[0],0.f)) | ((unsigned int)f2bf(fmaxf(acc[1],0.f)) << 16);
            unsigned int hi = (unsigned int)f2bf(fmaxf(acc[2],0.f)) | ((unsigned int)f2bf(fmaxf(acc[3],0.f)) << 16);
            int byte = r16*1024 + (mt*16 + g4*4)*2; byte ^= ((r16 & 7) << 4);
            uint2v vv = {lo, hi};
            *reinterpret_cast<uint2v*>(h1b + byte) = vv;
        }
    }
    __syncthreads();

    {
        int mt0 = wv*2, mt1 = wv*2 + 1;
        floatx4 acc0 = *reinterpret_cast<const floatx4*>(l2b + mt0*16 + g4*4);
        floatx4 acc1 = *reinterpret_cast<const floatx4*>(l2b + mt1*16 + g4*4);
        const unsigned short* wp0 = l2wb + (mt0*16 + r16)*512 + g4*8;
        const unsigned short* wp1 = l2wb + (mt1*16 + r16)*512 + g4*8;
        for (int ks = 0; ks < 16; ++ks) {
            short8 bb = ldsfrag(h1b, 1024, r16, ks*32 + g4*8);
            const short8 a0 = *reinterpret_cast<const short8*>(wp0 + ks*32);
            const short8 a1 = *reinterpret_cast<const short8*>(wp1 + ks*32);
            acc0 = __builtin_amdgcn_mfma_f32_16x16x32_bf16(a0, bb, acc0, 0, 0, 0);
            acc1 = __builtin_amdgcn_mfma_f32_16x16x32_bf16(a1, bb, acc1, 0, 0, 0);
        }
        const floatx4 w0 = *reinterpret_cast<const floatx4*>(l3w + mt0*16 + g4*4);
        const floatx4 w1 = *reinterpret_cast<const floatx4*>(l3w + mt1*16 + g4*4);
        float p = fmaxf(acc0[0],0.f)*w0[0] + fmaxf(acc0[1],0.f)*w0[1]
                + fmaxf(acc0[2],0.f)*w0[2] + fmaxf(acc0[3],0.f)*w0[3]
                + fmaxf(acc1[0],0.f)*w1[0] + fmaxf(acc1[1],0.f)*w1[1]
                + fmaxf(acc1[2],0.f)*w1[2] + fmaxf(acc1[3],0.f)*w1[3];
        p += __shfl_xor(p, 16);
        p += __shfl_xor(p, 32);
        if (g4 == 0) fp[wv*16 + r16] = p;
    }
    __syncthreads();

    floatx4 h0r = {0,0,0,0};
    floatx4 gR1 = {0,0,0,0}, gZ1 = {0,0,0,0}, gN1 = {0,0,0,0};
    floatx4 bihR, bihZ, bihN, bhhR, bhhZ, bhhN;
    if (wv < 2) {
        const int hf = wv;
        const int fb = hf*16 + g4*4;
        bihR = *reinterpret_cast<const floatx4*>(cbih + fb);
        bihZ = *reinterpret_cast<const floatx4*>(cbih + 32 + fb);
        bihN = *reinterpret_cast<const floatx4*>(cbih + 64 + fb);
        bhhR = *reinterpret_cast<const floatx4*>(cbhh + fb);
        bhhZ = *reinterpret_cast<const floatx4*>(cbhh + 32 + fb);
        bhhN = *reinterpret_cast<const floatx4*>(cbhh + 64 + fb);
        short8 bx0 = ldsfrag(xib, 128, r16, g4*8);
        short8 bx1 = ldsfrag(xib, 128, r16, 32 + g4*8);
        short8 cx0 = ldsfrag(xib, 128, 16 + r16, g4*8);
        short8 cx1 = ldsfrag(xib, 128, 16 + r16, 32 + g4*8);
        floatx4 gR0 = {0,0,0,0}, gZ0 = {0,0,0,0}, gN0 = {0,0,0,0};
        #pragma unroll
        for (int p = 0; p < 2; ++p) {
            const short8 aR = *reinterpret_cast<const short8*>(cwihb + ((hf    )*16 + r16)*64 + p*32 + g4*8);
            const short8 aZ = *reinterpret_cast<const short8*>(cwihb + ((2+hf  )*16 + r16)*64 + p*32 + g4*8);
            const short8 aN = *reinterpret_cast<const short8*>(cwihb + ((4+hf  )*16 + r16)*64 + p*32 + g4*8);
            short8 b0f = p ? bx1 : bx0;
            short8 b1f = p ? cx1 : cx0;
            gR0 = __builtin_amdgcn_mfma_f32_16x16x32_bf16(aR, b0f, gR0, 0, 0, 0);
            gZ0 = __builtin_amdgcn_mfma_f32_16x16x32_bf16(aZ, b0f, gZ0, 0, 0, 0);
            gN0 = __builtin_amdgcn_mfma_f32_16x16x32_bf16(aN, b0f, gN0, 0, 0, 0);
            gR1 = __builtin_amdgcn_mfma_f32_16x16x32_bf16(aR, b1f, gR1, 0, 0, 0);
            gZ1 = __builtin_amdgcn_mfma_f32_16x16x32_bf16(aZ, b1f, gZ1, 0, 0, 0);
            gN1 = __builtin_amdgcn_mfma_f32_16x16x32_bf16(aN, b1f, gN1, 0, 0, 0);
        }
        #pragma unroll
        for (int q = 0; q < 4; ++q) {
            float r = sigm(gR0[q] + bihR[q] + bhhR[q]);
            float z = sigm(gZ0[q] + bihZ[q] + bhhZ[q]);
            float n = tanhfast(gN0[q] + bihN[q] + r*bhhN[q]);
            h0r[q] = (1.0f - z)*n;
        }
        unsigned int lo = (unsigned int)f2bf(h0r[0]) | ((unsigned int)f2bf(h0r[1]) << 16);
        unsigned int hi = (unsigned int)f2bf(h0r[2]) | ((unsigned int)f2bf(h0r[3]) << 16);
        uint2v vv = {lo, hi};
        int byte = r16*128 + fb*2; byte ^= ((r16 & 7) << 4);
        *reinterpret_cast<uint2v*>(h0b + byte) = vv;
    }
    __syncthreads();
    if (wv < 2) {
        const int hf = wv;
        const int fb = hf*16 + g4*4;
        short8 bh = ldsfrag(h0b, 128, r16, g4*8);
        const short8 aR = *reinterpret_cast<const short8*>(cwhhb + ((hf    )*16 + r16)*32 + g4*8);
        const short8 aZ = *reinterpret_cast<const short8*>(cwhhb + ((2+hf  )*16 + r16)*32 + g4*8);
        const short8 aN = *reinterpret_cast<const short8*>(cwhhb + ((4+hf  )*16 + r16)*32 + g4*8);
        floatx4 hR = {0,0,0,0}, hZ = {0,0,0,0}, hN = {0,0,0,0};
        hR = __builtin_amdgcn_mfma_f32_16x16x32_bf16(aR, bh, hR, 0, 0, 0);
        hZ = __builtin_amdgcn_mfma_f32_16x16x32_bf16(aZ, bh, hZ, 0, 0, 0);
        hN = __builtin_amdgcn_mfma_f32_16x16x32_bf16(aN, bh, hN, 0, 0, 0);
        floatx4 hn;
        #pragma unroll
        for (int q = 0; q < 4; ++q) {
            float r = sigm(gR1[q] + bihR[q] + hR[q] + bhhR[q]);
            float z = sigm(gZ1[q] + bihZ[q] + hZ[q] + bhhZ[q]);
            float n = tanhfast(gN1[q] + bihN[q] + r*(hN[q] + bhhN[q]));
            hn[q] = (1.0f - z)*n + z*h0r[q];
        }
        unsigned int lo = (unsigned int)f2bf(hn[0]) | ((unsigned int)f2bf(hn[1]) << 16);
        unsigned int hi = (unsigned int)f2bf(hn[2]) | ((unsigned int)f2bf(hn[3]) << 16);
        uint2v vv = {lo, hi};
        int byte = r16*128 + fb*2; byte ^= ((r16 & 7) << 4);
        *reinterpret_cast<uint2v*>(hqb + byte) = vv;
    }
    __syncthreads();

    {
        short8 bq = ldsfrag(hqb, 128, r16, g4*8);
        #pragma unroll
        for (int j = 0; j < 4; ++j) {
            int mt = wv*4 + j;
            const short8 a = *reinterpret_cast<const short8*>(cf1wb + (mt*16 + r16)*32 + g4*8);
            floatx4 acc = *reinterpret_cast<const floatx4*>(cf1b + mt*16 + g4*4);
            acc = __builtin_amdgcn_mfma_f32_16x16x32_bf16(a, bq, acc, 0, 0, 0);
            unsigned int lo = (unsigned int)f2bf(fmaxf(acc[0],0.f)) | ((unsigned int)f2bf(fmaxf(acc[1],0.f)) << 16);
            unsigned int hi = (unsigned int)f2bf(fmaxf(acc[2],0.f)) | ((unsigned int)f2bf(fmaxf(acc[3],0.f)) << 16);
            int byte = r16*1024 + (mt*16 + g4*4)*2; byte ^= ((r16 & 7) << 4);
            uint2v vv = {lo, hi};
            *reinterpret_cast<uint2v*>(h1b + byte) = vv;
        }
    }
    __syncthreads();

    {
        int mt0 = wv*2, mt1 = wv*2 + 1;
        floatx4 acc0 = *reinterpret_cast<const floatx4*>(cf2b + mt0*16 + g4*4);
        floatx4 acc1 = *reinterpret_cast<const floatx4*>(cf2b + mt1*16 + g4*4);
        const unsigned short* wp0 = cf2wb + (mt0*16 + r16)*512 + g4*8;
        const unsigned short* wp1 = cf2wb + (mt1*16 + r16)*512 + g4*8;
        for (int ks = 0; ks < 16; ++ks) {
            short8 bb = ldsfrag(h1b, 1024, r16, ks*32 + g4*8);
            const short8 a0 = *reinterpret_cast<const short8*>(wp0 + ks*32);
            const short8 a1 = *reinterpret_cast<const short8*>(wp1 + ks*32);
            acc0 = __builtin_amdgcn_mfma_f32_16x16x32_bf16(a0, bb, acc0, 0, 0, 0);
            acc1 = __builtin_amdgcn_mfma_f32_16x16x32_bf16(a1, bb, acc1, 0, 0, 0);
        }
        const floatx4 w0 = *reinterpret_cast<const floatx4*>(cf3w + mt0*16 + g4*4);
        const floatx4 w1 = *reinterpret_cast<const floatx4*>(cf3w + mt1*16 + g4*4);
        float p = fmaxf(acc0[0],0.f)*w0[0] + fmaxf(acc0[1],0.f)*w0[1]
                + fmaxf(acc0[2],0.f)*w0[2] + fmaxf(acc0[3],0.f)*w0[3]
                + fmaxf(acc1[0],0.f)*w1[0] + fmaxf(acc1[1],0.f)*w1[1]
                + fmaxf(acc1[2],0.f)*w1[2] + fmaxf(acc1[3],0.f)*w1[3];
        p += __shfl_xor(p, 16);
        p += __shfl_xor(p, 32);
        if (g4 == 0) qp[wv*16 + r16] = p;
    }
    __syncthreads();

    if (tid < 16) {
        float f = l3b[0], qz = cf3b[0];
        #pragma unroll
        for (int w = 0; w < 8; ++w) { f += fp[w*16 + tid]; qz += qp[w*16 + tid]; }
        outq[b0 + tid] = f + qz;
    }
}

extern "C" void kernel_launch(void* const* d_in, const int* in_sizes, int n_in,
                              void* d_out, int out_size, void* d_ws, size_t ws_size,
                              hipStream_t stream)
{
    (void)in_sizes; (void)n_in; (void)out_size; (void)ws_size;
    const float* x     = (const float*)d_in[0];
    const float* a_wih = (const float*)d_in[1];
    const float* a_whh = (const float*)d_in[2];
    const float* a_bih = (const float*)d_in[3];
    const float* a_bhh = (const float*)d_in[4];
    const float* a1w   = (const float*)d_in[5];
    const float* a1b   = (const float*)d_in[6];
    const float* a2w   = (const float*)d_in[7];
    const float* a2b   = (const float*)d_in[8];
    const float* a3w   = (const float*)d_in[9];
    const float* a3b   = (const float*)d_in[10];
    const float* cwih  = (const float*)d_in[11];
    const float* cwhh  = (const float*)d_in[12];
    const float* cbih  = (const float*)d_in[13];
    const float* cbhh  = (const float*)d_in[14];
    const float* cf1w  = (const float*)d_in[15];
    const float* cf1b  = (const float*)d_in[16];
    const float* cf2w  = (const float*)d_in[17];
    const float* cf2b  = (const float*)d_in[18];
    const float* cf3w  = (const float*)d_in[19];
    const float* cf3b  = (const float*)d_in[20];
    const float* l1w   = (const float*)d_in[21];
    const float* l1b   = (const float*)d_in[22];
    const float* l2w   = (const float*)d_in[23];
    const float* l2b   = (const float*)d_in[24];
    const float* l3w   = (const float*)d_in[25];
    const float* l3b   = (const float*)d_in[26];

    float* sa = (float*)d_ws;
    unsigned short* wihb  = (unsigned short*)((char*)d_ws + WS_WIHB);
    unsigned short* whhb  = (unsigned short*)((char*)d_ws + WS_WHHB);
    unsigned short* w1b   = (unsigned short*)((char*)d_ws + WS_W1B);
    unsigned short* w2b   = (unsigned short*)((char*)d_ws + WS_W2B);
    unsigned short* l1wb  = (unsigned short*)((char*)d_ws + WS_L1WB);
    unsigned short* l2wb  = (unsigned short*)((char*)d_ws + WS_L2WB);
    unsigned short* cf1wb = (unsigned short*)((char*)d_ws + WS_CF1WB);
    unsigned short* cf2wb = (unsigned short*)((char*)d_ws + WS_CF2WB);
    unsigned short* cwihb = (unsigned short*)((char*)d_ws + WS_CWIHB);
    unsigned short* cwhhb = (unsigned short*)((char*)d_ws + WS_CWHHB);
    float* out0 = (float*)d_out;
    float* outq = (float*)d_out + NB*NZ;

    hipLaunchKernelGGL(prep_kernel, dim3((PREP_N + 255)/256), dim3(256), 0, stream,
                       a_wih, a_whh, a1w, a2w, l1w, l2w, cf1w, cf2w, cwih, cwhh,
                       wihb, whhb, w1b, w2b, l1wb, l2wb, cf1wb, cf2wb, cwihb, cwhhb);
    hipLaunchKernelGGL(actor_mfma, dim3(NSEQ/32), dim3(256), 0, stream,
                       x, wihb, whhb, a_bih, a_bhh, w1b, a1b, w2b, a2b, a3w, a3b, sa, out0);
    hipLaunchKernelGGL(critic_mfma, dim3(NB/16), dim3(512), 0, stream,
                       x, sa, cwihb, cwhhb, cbih, cbhh, cf1wb, cf1b, cf2wb, cf2b, cf3w, cf3b,
                       l1wb, l1b, l2wb, l2b, l3w, l3b, outq);
}